// Round 4
// baseline (633.828 us; speedup 1.0000x reference)
//
#include <hip/hip_runtime.h>

// ---------- types ----------
typedef __bf16 bf16x8 __attribute__((ext_vector_type(8)));
typedef __bf16 bf16x4v __attribute__((ext_vector_type(4)));
typedef float  f32x4  __attribute__((ext_vector_type(4)));

#define LDS_AS(p) ((__attribute__((address_space(3))) void*)(p))
#define GLB_AS(p) ((const __attribute__((address_space(1))) void*)(p))

// ---------- batched weight f32 -> bf16 transposed: Wt[n][k] = W[k][n] ----------
struct TP { const float* s[7]; __bf16* d[7]; };
__global__ __launch_bounds__(256) void transpose_convert_all(TP p) {
  const float* __restrict__ W = p.s[blockIdx.z];
  __bf16* __restrict__ Wt = p.d[blockIdx.z];
  __shared__ float tile[32][33];
  const int tx = threadIdx.x & 31, ty = threadIdx.x >> 5;
  const int n0 = blockIdx.x * 32, k0 = blockIdx.y * 32;
#pragma unroll
  for (int j = 0; j < 4; ++j)
    tile[ty + j * 8][tx] = W[(size_t)(k0 + ty + j * 8) * 2048 + n0 + tx];
  __syncthreads();
#pragma unroll
  for (int j = 0; j < 4; ++j)
    Wt[(size_t)(n0 + ty + j * 8) * 2048 + k0 + tx] = (__bf16)tile[tx][ty + j * 8];
}

// ---------- RMSNorm: f32 in -> bf16 out, D=2048, one block per row ----------
__global__ __launch_bounds__(256) void rmsnorm_k(
    const float* __restrict__ x, const float* __restrict__ scale,
    __bf16* __restrict__ out) {
  const int row = blockIdx.x, t = threadIdx.x;
  const float4* xr = (const float4*)(x + (size_t)row * 2048);
  float4 a = xr[t], b2 = xr[t + 256];
  float ss = a.x * a.x + a.y * a.y + a.z * a.z + a.w * a.w +
             b2.x * b2.x + b2.y * b2.y + b2.z * b2.z + b2.w * b2.w;
#pragma unroll
  for (int ofs = 32; ofs; ofs >>= 1) ss += __shfl_xor(ss, ofs, 64);
  __shared__ float red[4];
  if ((t & 63) == 0) red[t >> 6] = ss;
  __syncthreads();
  ss = red[0] + red[1] + red[2] + red[3];
  const float rs = rsqrtf(ss * (1.f / 2048.f) + 1e-5f);
  const float4* sr = (const float4*)scale;
  float4 s1 = sr[t], s2 = sr[t + 256];
  __bf16* orow = out + (size_t)row * 2048;
  orow[t * 4 + 0] = (__bf16)(a.x * rs * s1.x);
  orow[t * 4 + 1] = (__bf16)(a.y * rs * s1.y);
  orow[t * 4 + 2] = (__bf16)(a.z * rs * s1.z);
  orow[t * 4 + 3] = (__bf16)(a.w * rs * s1.w);
  orow[(t + 256) * 4 + 0] = (__bf16)(b2.x * rs * s2.x);
  orow[(t + 256) * 4 + 1] = (__bf16)(b2.y * rs * s2.y);
  orow[(t + 256) * 4 + 2] = (__bf16)(b2.z * rs * s2.z);
  orow[(t + 256) * 4 + 3] = (__bf16)(b2.w * rs * s2.w);
}

// ---------- GEMM: C[M,N] = A[M,K] @ Bt[N,K]^T, dbuf single-barrier (128^2) ----
// + T1 XCD-chunked blockIdx swizzle (all call sites: 512 blocks, 512%8==0).
template <bool OUTF32, bool HASBIAS, bool HASRES, bool SILU>
__global__ __launch_bounds__(256) void gemm_bt(
    const __bf16* __restrict__ A, const __bf16* __restrict__ Bt,
    const float* __restrict__ bias, const float* __restrict__ res,
    const __bf16* __restrict__ ew, void* __restrict__ Cout,
    int M, int N, int Kd) {
  __shared__ __attribute__((aligned(16))) __bf16 As[2][128 * 32];
  __shared__ __attribute__((aligned(16))) __bf16 Bs[2][128 * 32];
  const int tid = threadIdx.x;
  const int w = tid >> 6, l = tid & 63;
  const int flat = blockIdx.y * gridDim.x + blockIdx.x;
  const int nwg = gridDim.x * gridDim.y;          // 512 at all call sites
  const int swz = (flat & 7) * (nwg >> 3) + (flat >> 3);
  const int bx = swz % gridDim.x, by = swz / gridDim.x;
  const int M0 = by * 128, N0 = bx * 128;
  const int wr = w >> 1, wc = w & 1;
  const int lm = l & 15, lq = l >> 4;

  f32x4 acc[4][4];
#pragma unroll
  for (int mt = 0; mt < 4; ++mt)
#pragma unroll
    for (int nt = 0; nt < 4; ++nt)
#pragma unroll
      for (int e = 0; e < 4; ++e) acc[mt][nt][e] = 0.f;

  const int offA0 = (w * 2 + 0) * 1024 + l * 16;
  const int offA1 = (w * 2 + 1) * 1024 + l * 16;
  const int row0 = offA0 >> 6, kb0 = offA0 & 63;
  const int row1 = offA1 >> 6, kb1 = offA1 & 63;
  const int nIt = Kd >> 5;

  auto stage = [&](int k0, int bsel) {
    const char* ga0 = (const char*)(A + (size_t)(M0 + row0) * Kd + k0) + kb0;
    const char* ga1 = (const char*)(A + (size_t)(M0 + row1) * Kd + k0) + kb1;
    const char* gb0 = (const char*)(Bt + (size_t)(N0 + row0) * Kd + k0) + kb0;
    const char* gb1 = (const char*)(Bt + (size_t)(N0 + row1) * Kd + k0) + kb1;
    __builtin_amdgcn_global_load_lds(GLB_AS(ga0), LDS_AS(((char*)As[bsel]) + (w * 2 + 0) * 1024), 16, 0, 0);
    __builtin_amdgcn_global_load_lds(GLB_AS(ga1), LDS_AS(((char*)As[bsel]) + (w * 2 + 1) * 1024), 16, 0, 0);
    __builtin_amdgcn_global_load_lds(GLB_AS(gb0), LDS_AS(((char*)Bs[bsel]) + (w * 2 + 0) * 1024), 16, 0, 0);
    __builtin_amdgcn_global_load_lds(GLB_AS(gb1), LDS_AS(((char*)Bs[bsel]) + (w * 2 + 1) * 1024), 16, 0, 0);
  };

  stage(0, 0);
  for (int it = 0; it < nIt; ++it) {
    __syncthreads();
    if (it + 1 < nIt) stage((it + 1) * 32, (it + 1) & 1);
    const __bf16* Ab = As[it & 1];
    const __bf16* Bb = Bs[it & 1];
    bf16x8 af[4], bfr[4];
#pragma unroll
    for (int mt = 0; mt < 4; ++mt)
      af[mt] = *(const bf16x8*)(Ab + (wr * 64 + mt * 16 + lm) * 32 + lq * 8);
#pragma unroll
    for (int nt = 0; nt < 4; ++nt)
      bfr[nt] = *(const bf16x8*)(Bb + (wc * 64 + nt * 16 + lm) * 32 + lq * 8);
#pragma unroll
    for (int mt = 0; mt < 4; ++mt)
#pragma unroll
      for (int nt = 0; nt < 4; ++nt)
        acc[mt][nt] = __builtin_amdgcn_mfma_f32_16x16x32_bf16(af[mt], bfr[nt], acc[mt][nt], 0, 0, 0);
  }

  const int lr = lq * 4;
#pragma unroll
  for (int mt = 0; mt < 4; ++mt) {
#pragma unroll
    for (int nt = 0; nt < 4; ++nt) {
      const int col = N0 + wc * 64 + nt * 16 + lm;
      float bv = 0.f;
      if (HASBIAS) bv = bias[col];
#pragma unroll
      for (int i = 0; i < 4; ++i) {
        const int row = M0 + wr * 64 + mt * 16 + lr + i;
        const size_t off = (size_t)row * N + col;
        float v = acc[mt][nt][i] + bv;
        if (HASRES) v += res[off];
        if (SILU) {
          const float x1v = (float)ew[off];
          v = x1v * (1.f / (1.f + __expf(-x1v))) * v;
        }
        if (OUTF32) ((float*)Cout)[off] = v;
        else ((__bf16*)Cout)[off] = (__bf16)v;
      }
    }
  }
}

// ---------- fused QKV GEMM: 256^2 tile, BK=64, 8 waves, 8-phase counted-vmcnt ----
// Read distribution per K-tile (m201 balance): ph0 = A-half0(8)+B01(4) with
// lgkmcnt(8) pre-barrier hint; ph1 = B23(4); ph2 = A-half1(8); ph3 = 0.
// Stage map (slot s re-staged only after all reads of s drained by a prior
// phase's pre-MFMA lgkmcnt(0)): ph0 -> slot3(t+1, buf^1); ph2 -> slot0(t+2);
// ph3 -> slot1+slot2(t+2). vmcnt(6) at ph3: 14 outstanding, drains oldest 8
// = tile t+1 complete (incl. slot3 from ph0(t)).
__global__ __launch_bounds__(512, 2) void gemm_qkv(
    const __bf16* __restrict__ A, const __bf16* __restrict__ Bt,
    const float* __restrict__ bq, const float* __restrict__ bk,
    const float* __restrict__ bv,
    __bf16* __restrict__ Qout, __bf16* __restrict__ Kout,
    __bf16* __restrict__ Vtout, int Kd) {
  __shared__ __attribute__((aligned(16))) char lds[2][4][16384];

  const int tid = threadIdx.x;
  const int w = tid >> 6, l = tid & 63;
  const int wr = w >> 2, wc = w & 3;
  const int lm = l & 15, lq = l >> 4;

  int bid = blockIdx.y * 24 + blockIdx.x;
  bid = (bid & 7) * 48 + (bid >> 3);
  const int bx = bid % 24, by = bid / 24;
  const int N0 = bx * 256, M0 = by * 256;

  const int srow = w * 8 + (l >> 3);
  const int scol = ((l & 7) ^ (l >> 3)) * 8;
  const __bf16* aS = A + (size_t)(M0 + srow) * Kd + scol;
  const __bf16* bS = Bt + (size_t)(N0 + srow) * Kd + scol;

  auto stageHT = [&](int t, int s, int db) {
    char* dst = lds[db][s] + w * 1024;
    const __bf16* src = (s >= 2) ? (aS + (size_t)(s - 2) * 128 * Kd + t * 64)
                                 : (bS + (size_t)s * 128 * Kd + t * 64);
    __builtin_amdgcn_global_load_lds(GLB_AS(src), LDS_AS(dst), 16, 0, 0);
    __builtin_amdgcn_global_load_lds(GLB_AS(src + (size_t)64 * Kd), LDS_AS(dst + 8192), 16, 0, 0);
  };

  f32x4 acc[8][4];
#pragma unroll
  for (int m = 0; m < 8; ++m)
#pragma unroll
    for (int n = 0; n < 4; ++n)
#pragma unroll
      for (int e = 0; e < 4; ++e) acc[m][n][e] = 0.f;

  const int swzr = (lm & 7) << 4;
  const int c0 = (lq * 16) ^ swzr;
  const int c1 = ((64 + lq * 16)) ^ swzr;
  const int arow = lm * 128;
  const int brow = ((wc & 1) * 64 + lm) * 128;

  stageHT(0, 0, 0); stageHT(0, 1, 0); stageHT(0, 2, 0); stageHT(0, 3, 0);
  stageHT(1, 0, 1); stageHT(1, 1, 1); stageHT(1, 2, 1);
  asm volatile("s_waitcnt vmcnt(6)" ::: "memory");
  __builtin_amdgcn_s_barrier();

  const int NT = Kd >> 6;
  bf16x8 af[4][2], bfr[4][2];

#define BAR()                                            \
  do {                                                   \
    asm volatile("" ::: "memory");                       \
    __builtin_amdgcn_s_barrier();                        \
    asm volatile("" ::: "memory");                       \
  } while (0)

#define MFMA_QUAD(MB, NB)                                                          \
  do {                                                                             \
    _Pragma("unroll") for (int m = 0; m < 4; ++m)                                  \
      _Pragma("unroll") for (int n = 0; n < 2; ++n) {                              \
        acc[(MB) + m][(NB) + n] = __builtin_amdgcn_mfma_f32_16x16x32_bf16(         \
            af[m][0], bfr[(NB) + n][0], acc[(MB) + m][(NB) + n], 0, 0, 0);         \
        acc[(MB) + m][(NB) + n] = __builtin_amdgcn_mfma_f32_16x16x32_bf16(         \
            af[m][1], bfr[(NB) + n][1], acc[(MB) + m][(NB) + n], 0, 0, 0);         \
      }                                                                            \
  } while (0)

#define TILE_BODY(T, BUF)                                                       \
  do {                                                                          \
    const char* Ab = lds[BUF][2 + wr];                                          \
    const char* Bb = lds[BUF][wc >> 1];                                         \
    /* ph0: read A-half0(8)+B01(4); stage slot3(T+1)->buf^1; MFMA(0,0) */       \
    _Pragma("unroll") for (int m = 0; m < 4; ++m) {                             \
      af[m][0] = *(const bf16x8*)(Ab + arow + m * 2048 + c0);                   \
      af[m][1] = *(const bf16x8*)(Ab + arow + m * 2048 + c1);                   \
    }                                                                           \
    _Pragma("unroll") for (int n = 0; n < 2; ++n) {                             \
      bfr[n][0] = *(const bf16x8*)(Bb + brow + n * 2048 + c0);                  \
      bfr[n][1] = *(const bf16x8*)(Bb + brow + n * 2048 + c1);                  \
    }                                                                           \
    if ((T) + 1 < NT) stageHT((T) + 1, 3, (BUF) ^ 1);                           \
    asm volatile("s_waitcnt lgkmcnt(8)" ::: "memory");                          \
    BAR();                                                                      \
    asm volatile("s_waitcnt lgkmcnt(0)" ::: "memory");                          \
    __builtin_amdgcn_s_setprio(1);                                              \
    MFMA_QUAD(0, 0);                                                            \
    __builtin_amdgcn_s_setprio(0);                                              \
    BAR();                                                                      \
    /* ph1: read B23(4); MFMA(0,2) */                                           \
    _Pragma("unroll") for (int n = 2; n < 4; ++n) {                             \
      bfr[n][0] = *(const bf16x8*)(Bb + brow + n * 2048 + c0);                  \
      bfr[n][1] = *(const bf16x8*)(Bb + brow + n * 2048 + c1);                  \
    }                                                                           \
    BAR();                                                                      \
    asm volatile("s_waitcnt lgkmcnt(0)" ::: "memory");                          \
    __builtin_amdgcn_s_setprio(1);                                              \
    MFMA_QUAD(0, 2);                                                            \
    __builtin_amdgcn_s_setprio(0);                                              \
    BAR();                                                                      \
    /* ph2: read A-half1(8); stage slot0(T+2); MFMA(4,0) */                     \
    _Pragma("unroll") for (int m = 0; m < 4; ++m) {                             \
      af[m][0] = *(const bf16x8*)(Ab + arow + (m + 4) * 2048 + c0);             \
      af[m][1] = *(const bf16x8*)(Ab + arow + (m + 4) * 2048 + c1);             \
    }                                                                           \
    if ((T) + 2 < NT) stageHT((T) + 2, 0, BUF);                                 \
    BAR();                                                                      \
    asm volatile("s_waitcnt lgkmcnt(0)" ::: "memory");                          \
    __builtin_amdgcn_s_setprio(1);                                              \
    MFMA_QUAD(4, 0);                                                            \
    __builtin_amdgcn_s_setprio(0);                                              \
    BAR();                                                                      \
    /* ph3: stage slot1+slot2(T+2); MFMA(4,2); counted vmcnt */                 \
    if ((T) + 2 < NT) { stageHT((T) + 2, 1, BUF); stageHT((T) + 2, 2, BUF); }   \
    BAR();                                                                      \
    __builtin_amdgcn_s_setprio(1);                                              \
    MFMA_QUAD(4, 2);                                                            \
    __builtin_amdgcn_s_setprio(0);                                              \
    if ((T) + 2 < NT) { asm volatile("s_waitcnt vmcnt(6)" ::: "memory"); }      \
    else { asm volatile("s_waitcnt vmcnt(0)" ::: "memory"); }                   \
    BAR();                                                                      \
  } while (0)

  for (int tp = 0; tp < NT; tp += 2) {
    TILE_BODY(tp, 0);
    TILE_BODY(tp + 1, 1);
  }
#undef TILE_BODY
#undef MFMA_QUAD
#undef BAR

  const int seg = N0 >> 11;               // 0:Q 1:K 2:V
  const int nbase = N0 & 2047;
  const float* bb = (seg == 0) ? bq : ((seg == 1) ? bk : bv);
  if (seg < 2) {
    __bf16* dst = (seg == 0) ? Qout : Kout;
#pragma unroll
    for (int m = 0; m < 8; ++m) {
#pragma unroll
      for (int n = 0; n < 4; ++n) {
        const int col = nbase + wc * 64 + n * 16 + lm;
        const float bvv = bb[col];
#pragma unroll
        for (int i = 0; i < 4; ++i) {
          const int row = M0 + wr * 128 + m * 16 + lq * 4 + i;
          dst[(size_t)row * 2048 + col] = (__bf16)(acc[m][n][i] + bvv);
        }
      }
    }
  } else {
#pragma unroll
    for (int m = 0; m < 8; ++m) {
#pragma unroll
      for (int n = 0; n < 4; ++n) {
        const int col = nbase + wc * 64 + n * 16 + lm;
        const float bvv = bb[col];
        const int rw0 = M0 + wr * 128 + m * 16 + lq * 4;
        const int bidx = rw0 >> 11, tok = rw0 & 2047;
        bf16x4v pk;
#pragma unroll
        for (int i = 0; i < 4; ++i) pk[i] = (__bf16)(acc[m][n][i] + bvv);
        *(bf16x4v*)(Vtout + ((size_t)(bidx * 2048 + col)) * 2048 + tok) = pk;
      }
    }
  }
}

// ---------- MFMA flash attention v5 + T5 setprio + XCD-chunked swizzle -------
__global__ __launch_bounds__(256, 2) void attn_mfma(
    const __bf16* __restrict__ Q, const __bf16* __restrict__ K,
    const __bf16* __restrict__ Vt, __bf16* __restrict__ O) {
  __shared__ __attribute__((aligned(16))) char KsL[2][16 * 1024];
  __shared__ __attribute__((aligned(16))) char VsL[2][16 * 1024];

  const int t = threadIdx.x;
  const int w = t >> 6, l = t & 63;
  const int lm = l & 15, quad = l >> 4;
  const int flat = (blockIdx.z * gridDim.y + blockIdx.y) * gridDim.x + blockIdx.x;
  const int swz = (flat & 7) * 64 + (flat >> 3);
  const int b = swz >> 8;
  const int h = (swz >> 4) & 15;
  const int q0 = (swz & 15) * 128;
  const size_t Ds = 2048;
  const size_t hoff = (size_t)h * 128;
  const size_t bbase = (size_t)b * 2048;
  const int sl16 = ((lm << 2) | quad) * 16;
  const float SCL = 0.08838834764831845f * 1.4426950408889634f;

  const int krow = l >> 2, kcol = (l & 3) * 8;
  const int vth = l & 3, vd = l >> 2;

  bf16x8 qf[2][4];
#pragma unroll
  for (int ntq = 0; ntq < 2; ++ntq)
#pragma unroll
    for (int ks = 0; ks < 4; ++ks)
      qf[ntq][ks] = *(const bf16x8*)(Q + (bbase + q0 + w * 32 + ntq * 16 + lm) * Ds + hoff + ks * 32 + quad * 8);

  f32x4 oacc[2][8];
#pragma unroll
  for (int ntq = 0; ntq < 2; ++ntq)
#pragma unroll
    for (int nv = 0; nv < 8; ++nv)
#pragma unroll
      for (int e = 0; e < 4; ++e) oacc[ntq][nv][e] = 0.f;
  float lpart[2] = {0.f, 0.f};

  bf16x8 vreg[4];

  auto loadV = [&](int kt) {
#pragma unroll
    for (int i = 0; i < 4; ++i) {
      const int chunk = w * 4 + i;
      const int nv = chunk >> 1, c = chunk & 1;
      vreg[i] = *(const bf16x8*)(Vt + (bbase + hoff + nv * 16 + vd) * Ds + kt + c * 32 + vth * 8);
    }
  };
  auto stageK = [&](int kt, char* Kb) {
#pragma unroll
    for (int i = 0; i < 4; ++i) {
      const __bf16* src = K + (bbase + kt + i * 16 + krow) * Ds + hoff + w * 32 + kcol;
      __builtin_amdgcn_global_load_lds(GLB_AS(src), LDS_AS(Kb + (i * 4 + w) * 1024), 16, 0, 0);
    }
  };
  auto writeV = [&](char* Vb) {
    const int s0off = ((vd << 2) | ((vth & 1) * 2)) * 16 + (vth >> 1) * 8;
#pragma unroll
    for (int i = 0; i < 4; ++i) {
      char* base = Vb + (w * 4 + i) * 1024;
      uint4 u = *(const uint4*)&vreg[i];
      *(uint2*)(base + s0off) = make_uint2(u.x, u.y);
      *(uint2*)(base + s0off + 16) = make_uint2(u.z, u.w);
    }
  };

  loadV(0);
  stageK(0, KsL[0]);
  writeV(VsL[0]);

  for (int it = 0; it < 32; ++it) {
    __syncthreads();
    const int cur = it & 1;
    const bool more = (it + 1) < 32;
    if (more) { loadV((it + 1) * 64); stageK((it + 1) * 64, KsL[(it + 1) & 1]); }

    const char* Kb = KsL[cur];
    const char* Vb = VsL[cur];

    f32x4 st[4][2];
#pragma unroll
    for (int mtk = 0; mtk < 4; ++mtk)
#pragma unroll
      for (int ntq = 0; ntq < 2; ++ntq)
#pragma unroll
        for (int e = 0; e < 4; ++e) st[mtk][ntq][e] = 0.f;
    __builtin_amdgcn_s_setprio(1);
#pragma unroll
    for (int ks = 0; ks < 4; ++ks) {
#pragma unroll
      for (int mtk = 0; mtk < 4; ++mtk) {
        bf16x8 kf = *(const bf16x8*)(Kb + (mtk * 4 + ks) * 1024 + sl16);
        st[mtk][0] = __builtin_amdgcn_mfma_f32_16x16x32_bf16(kf, qf[0][ks], st[mtk][0], 0, 0, 0);
        st[mtk][1] = __builtin_amdgcn_mfma_f32_16x16x32_bf16(kf, qf[1][ks], st[mtk][1], 0, 0, 0);
      }
    }
    __builtin_amdgcn_s_setprio(0);

#pragma unroll
    for (int c = 0; c < 2; ++c) {
      bf16x8 pf[2];
#pragma unroll
      for (int ntq = 0; ntq < 2; ++ntq) {
#pragma unroll
        for (int half = 0; half < 2; ++half) {
          const f32x4 sv = st[c * 2 + half][ntq];
#pragma unroll
          for (int r = 0; r < 4; ++r) {
            const float p = exp2f(sv[r] * SCL);
            const __bf16 pb = (__bf16)p;
            pf[ntq][half * 4 + r] = pb;
            lpart[ntq] += (float)pb;
          }
        }
      }
      __builtin_amdgcn_s_setprio(1);
#pragma unroll
      for (int nv = 0; nv < 8; ++nv) {
        bf16x8 vf = *(const bf16x8*)(Vb + (nv * 2 + c) * 1024 + sl16);
        oacc[0][nv] = __builtin_amdgcn_mfma_f32_16x16x32_bf16(pf[0], vf, oacc[0][nv], 0, 0, 0);
        oacc[1][nv] = __builtin_amdgcn_mfma_f32_16x16x32_bf16(pf[1], vf, oacc[1][nv], 0, 0, 0);
      }
      __builtin_amdgcn_s_setprio(0);
    }

    if (more) writeV(VsL[(it + 1) & 1]);
  }

  float linv[2];
#pragma unroll
  for (int ntq = 0; ntq < 2; ++ntq) {
    float v = lpart[ntq];
    v += __shfl_xor(v, 16, 64);
    v += __shfl_xor(v, 32, 64);
    linv[ntq] = 1.f / v;
  }
  float oinv[2][4];
#pragma unroll
  for (int ntq = 0; ntq < 2; ++ntq)
#pragma unroll
    for (int r = 0; r < 4; ++r)
      oinv[ntq][r] = __shfl(linv[ntq], quad * 4 + r, 64);

#pragma unroll
  for (int ntq = 0; ntq < 2; ++ntq)
#pragma unroll
    for (int nv = 0; nv < 8; ++nv)
#pragma unroll
      for (int r = 0; r < 4; ++r) {
        const int qrow = q0 + w * 32 + ntq * 16 + quad * 4 + r;
        O[(bbase + qrow) * Ds + hoff + nv * 16 + lm] = (__bf16)(oacc[ntq][nv][r] * oinv[ntq][r]);
      }
}

// ---------- launch ----------
extern "C" void kernel_launch(void* const* d_in, const int* in_sizes, int n_in,
                              void* d_out, int out_size, void* d_ws, size_t ws_size,
                              hipStream_t stream) {
  const float* x      = (const float*)d_in[0];
  const float* Wq     = (const float*)d_in[1];
  const float* bq     = (const float*)d_in[2];
  const float* Wk     = (const float*)d_in[3];
  const float* bk     = (const float*)d_in[4];
  const float* Wv     = (const float*)d_in[5];
  const float* bv     = (const float*)d_in[6];
  const float* Wo     = (const float*)d_in[7];
  const float* bo     = (const float*)d_in[8];
  const float* scale1 = (const float*)d_in[9];
  const float* scale2 = (const float*)d_in[10];
  const float* W1     = (const float*)d_in[11];
  const float* W2     = (const float*)d_in[12];
  const float* W3     = (const float*)d_in[13];

  const int M = 4096, N = 2048, Kd = 2048;
  char* ws = (char*)d_ws;
  const size_t WT_B = (size_t)2048 * 2048 * 2;   // 8 MB
  const size_t ACT_B = (size_t)4096 * 2048 * 2;  // 16 MB
  __bf16* wt[7];
  size_t off = 0;
  for (int i = 0; i < 7; ++i) { wt[i] = (__bf16*)(ws + off); off += WT_B; }
  __bf16* hn1  = (__bf16*)(ws + off); off += ACT_B;
  __bf16* Qb   = (__bf16*)(ws + off); off += ACT_B;
  __bf16* Kb   = (__bf16*)(ws + off); off += ACT_B;
  __bf16* VtG  = (__bf16*)(ws + off); off += ACT_B;
  __bf16* attn = (__bf16*)(ws + off); off += ACT_B;
  __bf16* hn2  = (__bf16*)(ws + off); off += ACT_B;
  __bf16* x1b  = (__bf16*)(ws + off); off += ACT_B;
  __bf16* fmb  = (__bf16*)(ws + off); off += ACT_B;

  dim3 tb(256);
  {
    TP p;
    p.s[0] = Wq; p.s[1] = Wk; p.s[2] = Wv; p.s[3] = Wo; p.s[4] = W1; p.s[5] = W2; p.s[6] = W3;
    for (int i = 0; i < 7; ++i) p.d[i] = wt[i];
    transpose_convert_all<<<dim3(64, 64, 7), tb, 0, stream>>>(p);
  }

  rmsnorm_k<<<4096, tb, 0, stream>>>(x, scale1, hn1);

  gemm_qkv<<<dim3(6144 / 256, M / 256), dim3(512), 0, stream>>>(
      hn1, wt[0], bq, bk, bv, Qb, Kb, VtG, Kd);

  dim3 ag(2048 / 128, 16, 2);
  attn_mfma<<<ag, tb, 0, stream>>>(Qb, Kb, VtG, attn);

  dim3 gg(N / 128, M / 128);
  gemm_bt<true, true, true, false><<<gg, tb, 0, stream>>>(attn, wt[3], bo, x, nullptr, d_out, M, N, Kd);

  rmsnorm_k<<<4096, tb, 0, stream>>>((const float*)d_out, scale2, hn2);

  gemm_bt<false, false, false, false><<<gg, tb, 0, stream>>>(hn2, wt[4], nullptr, nullptr, nullptr, x1b, M, N, Kd);
  gemm_bt<false, false, false, true><<<gg, tb, 0, stream>>>(x1b, wt[5], nullptr, nullptr, x1b, fmb, M, N, Kd);
  gemm_bt<true, false, true, false><<<gg, tb, 0, stream>>>(fmb, wt[6], nullptr, x, nullptr, d_out, M, N, Kd);
}

// Round 5
// 628.679 us; speedup vs baseline: 1.0082x; 1.0082x over previous
//
#include <hip/hip_runtime.h>

// ---------- types ----------
typedef __bf16 bf16x8 __attribute__((ext_vector_type(8)));
typedef __bf16 bf16x4v __attribute__((ext_vector_type(4)));
typedef float  f32x4  __attribute__((ext_vector_type(4)));

#define LDS_AS(p) ((__attribute__((address_space(3))) void*)(p))
#define GLB_AS(p) ((const __attribute__((address_space(1))) void*)(p))

// ---------- batched weight f32 -> bf16 transposed: Wt[n][k] = W[k][n] ----------
struct TP { const float* s[7]; __bf16* d[7]; };
__global__ __launch_bounds__(256) void transpose_convert_all(TP p) {
  const float* __restrict__ W = p.s[blockIdx.z];
  __bf16* __restrict__ Wt = p.d[blockIdx.z];
  __shared__ float tile[32][33];
  const int tx = threadIdx.x & 31, ty = threadIdx.x >> 5;
  const int n0 = blockIdx.x * 32, k0 = blockIdx.y * 32;
#pragma unroll
  for (int j = 0; j < 4; ++j)
    tile[ty + j * 8][tx] = W[(size_t)(k0 + ty + j * 8) * 2048 + n0 + tx];
  __syncthreads();
#pragma unroll
  for (int j = 0; j < 4; ++j)
    Wt[(size_t)(n0 + ty + j * 8) * 2048 + k0 + tx] = (__bf16)tile[tx][ty + j * 8];
}

// ---------- RMSNorm: f32 in -> bf16 out, D=2048, one block per row ----------
__global__ __launch_bounds__(256) void rmsnorm_k(
    const float* __restrict__ x, const float* __restrict__ scale,
    __bf16* __restrict__ out) {
  const int row = blockIdx.x, t = threadIdx.x;
  const float4* xr = (const float4*)(x + (size_t)row * 2048);
  float4 a = xr[t], b2 = xr[t + 256];
  float ss = a.x * a.x + a.y * a.y + a.z * a.z + a.w * a.w +
             b2.x * b2.x + b2.y * b2.y + b2.z * b2.z + b2.w * b2.w;
#pragma unroll
  for (int ofs = 32; ofs; ofs >>= 1) ss += __shfl_xor(ss, ofs, 64);
  __shared__ float red[4];
  if ((t & 63) == 0) red[t >> 6] = ss;
  __syncthreads();
  ss = red[0] + red[1] + red[2] + red[3];
  const float rs = rsqrtf(ss * (1.f / 2048.f) + 1e-5f);
  const float4* sr = (const float4*)scale;
  float4 s1 = sr[t], s2 = sr[t + 256];
  __bf16* orow = out + (size_t)row * 2048;
  orow[t * 4 + 0] = (__bf16)(a.x * rs * s1.x);
  orow[t * 4 + 1] = (__bf16)(a.y * rs * s1.y);
  orow[t * 4 + 2] = (__bf16)(a.z * rs * s1.z);
  orow[t * 4 + 3] = (__bf16)(a.w * rs * s1.w);
  orow[(t + 256) * 4 + 0] = (__bf16)(b2.x * rs * s2.x);
  orow[(t + 256) * 4 + 1] = (__bf16)(b2.y * rs * s2.y);
  orow[(t + 256) * 4 + 2] = (__bf16)(b2.z * rs * s2.z);
  orow[(t + 256) * 4 + 3] = (__bf16)(b2.w * rs * s2.w);
}

// ---------- GEMM: C[M,N] = A[M,K] @ Bt[N,K]^T, dbuf single-barrier (128^2) ----
// + T1 XCD-chunked blockIdx swizzle (all call sites: 512 blocks, 512%8==0).
template <bool OUTF32, bool HASBIAS, bool HASRES, bool SILU>
__global__ __launch_bounds__(256) void gemm_bt(
    const __bf16* __restrict__ A, const __bf16* __restrict__ Bt,
    const float* __restrict__ bias, const float* __restrict__ res,
    const __bf16* __restrict__ ew, void* __restrict__ Cout,
    int M, int N, int Kd) {
  __shared__ __attribute__((aligned(16))) __bf16 As[2][128 * 32];
  __shared__ __attribute__((aligned(16))) __bf16 Bs[2][128 * 32];
  const int tid = threadIdx.x;
  const int w = tid >> 6, l = tid & 63;
  const int flat = blockIdx.y * gridDim.x + blockIdx.x;
  const int nwg = gridDim.x * gridDim.y;          // 512 at all call sites
  const int swz = (flat & 7) * (nwg >> 3) + (flat >> 3);
  const int bx = swz % gridDim.x, by = swz / gridDim.x;
  const int M0 = by * 128, N0 = bx * 128;
  const int wr = w >> 1, wc = w & 1;
  const int lm = l & 15, lq = l >> 4;

  f32x4 acc[4][4];
#pragma unroll
  for (int mt = 0; mt < 4; ++mt)
#pragma unroll
    for (int nt = 0; nt < 4; ++nt)
#pragma unroll
      for (int e = 0; e < 4; ++e) acc[mt][nt][e] = 0.f;

  const int offA0 = (w * 2 + 0) * 1024 + l * 16;
  const int offA1 = (w * 2 + 1) * 1024 + l * 16;
  const int row0 = offA0 >> 6, kb0 = offA0 & 63;
  const int row1 = offA1 >> 6, kb1 = offA1 & 63;
  const int nIt = Kd >> 5;

  auto stage = [&](int k0, int bsel) {
    const char* ga0 = (const char*)(A + (size_t)(M0 + row0) * Kd + k0) + kb0;
    const char* ga1 = (const char*)(A + (size_t)(M0 + row1) * Kd + k0) + kb1;
    const char* gb0 = (const char*)(Bt + (size_t)(N0 + row0) * Kd + k0) + kb0;
    const char* gb1 = (const char*)(Bt + (size_t)(N0 + row1) * Kd + k0) + kb1;
    __builtin_amdgcn_global_load_lds(GLB_AS(ga0), LDS_AS(((char*)As[bsel]) + (w * 2 + 0) * 1024), 16, 0, 0);
    __builtin_amdgcn_global_load_lds(GLB_AS(ga1), LDS_AS(((char*)As[bsel]) + (w * 2 + 1) * 1024), 16, 0, 0);
    __builtin_amdgcn_global_load_lds(GLB_AS(gb0), LDS_AS(((char*)Bs[bsel]) + (w * 2 + 0) * 1024), 16, 0, 0);
    __builtin_amdgcn_global_load_lds(GLB_AS(gb1), LDS_AS(((char*)Bs[bsel]) + (w * 2 + 1) * 1024), 16, 0, 0);
  };

  stage(0, 0);
  for (int it = 0; it < nIt; ++it) {
    __syncthreads();
    if (it + 1 < nIt) stage((it + 1) * 32, (it + 1) & 1);
    const __bf16* Ab = As[it & 1];
    const __bf16* Bb = Bs[it & 1];
    bf16x8 af[4], bfr[4];
#pragma unroll
    for (int mt = 0; mt < 4; ++mt)
      af[mt] = *(const bf16x8*)(Ab + (wr * 64 + mt * 16 + lm) * 32 + lq * 8);
#pragma unroll
    for (int nt = 0; nt < 4; ++nt)
      bfr[nt] = *(const bf16x8*)(Bb + (wc * 64 + nt * 16 + lm) * 32 + lq * 8);
#pragma unroll
    for (int mt = 0; mt < 4; ++mt)
#pragma unroll
      for (int nt = 0; nt < 4; ++nt)
        acc[mt][nt] = __builtin_amdgcn_mfma_f32_16x16x32_bf16(af[mt], bfr[nt], acc[mt][nt], 0, 0, 0);
  }

  const int lr = lq * 4;
#pragma unroll
  for (int mt = 0; mt < 4; ++mt) {
#pragma unroll
    for (int nt = 0; nt < 4; ++nt) {
      const int col = N0 + wc * 64 + nt * 16 + lm;
      float bv = 0.f;
      if (HASBIAS) bv = bias[col];
#pragma unroll
      for (int i = 0; i < 4; ++i) {
        const int row = M0 + wr * 64 + mt * 16 + lr + i;
        const size_t off = (size_t)row * N + col;
        float v = acc[mt][nt][i] + bv;
        if (HASRES) v += res[off];
        if (SILU) {
          const float x1v = (float)ew[off];
          v = x1v * (1.f / (1.f + __expf(-x1v))) * v;
        }
        if (OUTF32) ((float*)Cout)[off] = v;
        else ((__bf16*)Cout)[off] = (__bf16)v;
      }
    }
  }
}

// ---------- fused QKV GEMM: 256^2 tile, BK=64, 8 waves, 8-phase counted-vmcnt ----
// Round-2 body (best measured variant). qkv is structurally parked at ~140 us:
// 384 tiles @ 1 block/CU = 1.5 rounds (2T makespan, 75% packing); 2 blocks/CU
// impossible (acc=128 regs), tile-count rearrangements are zero-sum.
__global__ __launch_bounds__(512, 2) void gemm_qkv(
    const __bf16* __restrict__ A, const __bf16* __restrict__ Bt,
    const float* __restrict__ bq, const float* __restrict__ bk,
    const float* __restrict__ bv,
    __bf16* __restrict__ Qout, __bf16* __restrict__ Kout,
    __bf16* __restrict__ Vtout, int Kd) {
  __shared__ __attribute__((aligned(16))) char lds[2][4][16384];

  const int tid = threadIdx.x;
  const int w = tid >> 6, l = tid & 63;
  const int wr = w >> 2, wc = w & 3;
  const int lm = l & 15, lq = l >> 4;

  int bid = blockIdx.y * 24 + blockIdx.x;
  bid = (bid & 7) * 48 + (bid >> 3);
  const int bx = bid % 24, by = bid / 24;
  const int N0 = bx * 256, M0 = by * 256;

  const int srow = w * 8 + (l >> 3);
  const int scol = ((l & 7) ^ (l >> 3)) * 8;
  const __bf16* aS = A + (size_t)(M0 + srow) * Kd + scol;
  const __bf16* bS = Bt + (size_t)(N0 + srow) * Kd + scol;

  auto stageHT = [&](int t, int s, int db) {
    char* dst = lds[db][s] + w * 1024;
    const __bf16* src = (s >= 2) ? (aS + (size_t)(s - 2) * 128 * Kd + t * 64)
                                 : (bS + (size_t)s * 128 * Kd + t * 64);
    __builtin_amdgcn_global_load_lds(GLB_AS(src), LDS_AS(dst), 16, 0, 0);
    __builtin_amdgcn_global_load_lds(GLB_AS(src + (size_t)64 * Kd), LDS_AS(dst + 8192), 16, 0, 0);
  };

  f32x4 acc[8][4];
#pragma unroll
  for (int m = 0; m < 8; ++m)
#pragma unroll
    for (int n = 0; n < 4; ++n)
#pragma unroll
      for (int e = 0; e < 4; ++e) acc[m][n][e] = 0.f;

  const int swzr = (lm & 7) << 4;
  const int c0 = (lq * 16) ^ swzr;
  const int c1 = ((64 + lq * 16)) ^ swzr;
  const int arow = lm * 128;
  const int brow = ((wc & 1) * 64 + lm) * 128;

  stageHT(0, 0, 0); stageHT(0, 1, 0); stageHT(0, 2, 0); stageHT(0, 3, 0);
  stageHT(1, 0, 1); stageHT(1, 1, 1); stageHT(1, 2, 1);
  asm volatile("s_waitcnt vmcnt(6)" ::: "memory");
  __builtin_amdgcn_s_barrier();

  const int NT = Kd >> 6;
  bf16x8 af[4][2], bfr[4][2];

#define BAR()                                            \
  do {                                                   \
    asm volatile("" ::: "memory");                       \
    __builtin_amdgcn_s_barrier();                        \
    asm volatile("" ::: "memory");                       \
  } while (0)

#define MFMA_QUAD(MB, NB)                                                          \
  do {                                                                             \
    _Pragma("unroll") for (int m = 0; m < 4; ++m)                                  \
      _Pragma("unroll") for (int n = 0; n < 2; ++n) {                              \
        acc[(MB) + m][(NB) + n] = __builtin_amdgcn_mfma_f32_16x16x32_bf16(         \
            af[m][0], bfr[(NB) + n][0], acc[(MB) + m][(NB) + n], 0, 0, 0);         \
        acc[(MB) + m][(NB) + n] = __builtin_amdgcn_mfma_f32_16x16x32_bf16(         \
            af[m][1], bfr[(NB) + n][1], acc[(MB) + m][(NB) + n], 0, 0, 0);         \
      }                                                                            \
  } while (0)

#define TILE_BODY(T, BUF)                                                       \
  do {                                                                          \
    const char* Ab = lds[BUF][2 + wr];                                          \
    const char* Bb = lds[BUF][wc >> 1];                                         \
    /* ph0: read A-quad0 + all B; stage slot3(T+1)->buf^1; MFMA(0,0) */         \
    _Pragma("unroll") for (int m = 0; m < 4; ++m) {                             \
      af[m][0] = *(const bf16x8*)(Ab + arow + m * 2048 + c0);                   \
      af[m][1] = *(const bf16x8*)(Ab + arow + m * 2048 + c1);                   \
    }                                                                           \
    _Pragma("unroll") for (int n = 0; n < 4; ++n) {                             \
      bfr[n][0] = *(const bf16x8*)(Bb + brow + n * 2048 + c0);                  \
      bfr[n][1] = *(const bf16x8*)(Bb + brow + n * 2048 + c1);                  \
    }                                                                           \
    if ((T) + 1 < NT) stageHT((T) + 1, 3, (BUF) ^ 1);                           \
    BAR();                                                                      \
    __builtin_amdgcn_s_setprio(1);                                              \
    MFMA_QUAD(0, 0);                                                            \
    __builtin_amdgcn_s_setprio(0);                                              \
    asm volatile("s_waitcnt lgkmcnt(0)" ::: "memory");                          \
    BAR();                                                                      \
    /* ph1: stage slot0(T+2); MFMA(0,2) */                                      \
    if ((T) + 2 < NT) stageHT((T) + 2, 0, BUF);                                 \
    BAR();                                                                      \
    __builtin_amdgcn_s_setprio(1);                                              \
    MFMA_QUAD(0, 2);                                                            \
    __builtin_amdgcn_s_setprio(0);                                              \
    BAR();                                                                      \
    /* ph2: read A-quad1; stage slot1(T+2); MFMA(4,0) */                        \
    _Pragma("unroll") for (int m = 0; m < 4; ++m) {                             \
      af[m][0] = *(const bf16x8*)(Ab + arow + (m + 4) * 2048 + c0);             \
      af[m][1] = *(const bf16x8*)(Ab + arow + (m + 4) * 2048 + c1);             \
    }                                                                           \
    if ((T) + 2 < NT) stageHT((T) + 2, 1, BUF);                                 \
    BAR();                                                                      \
    __builtin_amdgcn_s_setprio(1);                                              \
    MFMA_QUAD(4, 0);                                                            \
    __builtin_amdgcn_s_setprio(0);                                              \
    asm volatile("s_waitcnt lgkmcnt(0)" ::: "memory");                          \
    BAR();                                                                      \
    /* ph3: stage slot2(T+2); MFMA(4,2); counted vmcnt */                       \
    if ((T) + 2 < NT) stageHT((T) + 2, 2, BUF);                                 \
    BAR();                                                                      \
    __builtin_amdgcn_s_setprio(1);                                              \
    MFMA_QUAD(4, 2);                                                            \
    __builtin_amdgcn_s_setprio(0);                                              \
    if ((T) + 2 < NT) { asm volatile("s_waitcnt vmcnt(6)" ::: "memory"); }      \
    else { asm volatile("s_waitcnt vmcnt(0)" ::: "memory"); }                   \
    BAR();                                                                      \
  } while (0)

  for (int tp = 0; tp < NT; tp += 2) {
    TILE_BODY(tp, 0);
    TILE_BODY(tp + 1, 1);
  }
#undef TILE_BODY
#undef MFMA_QUAD
#undef BAR

  const int seg = N0 >> 11;               // 0:Q 1:K 2:V
  const int nbase = N0 & 2047;
  const float* bb = (seg == 0) ? bq : ((seg == 1) ? bk : bv);
  if (seg < 2) {
    __bf16* dst = (seg == 0) ? Qout : Kout;
#pragma unroll
    for (int m = 0; m < 8; ++m) {
#pragma unroll
      for (int n = 0; n < 4; ++n) {
        const int col = nbase + wc * 64 + n * 16 + lm;
        const float bvv = bb[col];
#pragma unroll
        for (int i = 0; i < 4; ++i) {
          const int row = M0 + wr * 128 + m * 16 + lq * 4 + i;
          dst[(size_t)row * 2048 + col] = (__bf16)(acc[m][n][i] + bvv);
        }
      }
    }
  } else {
#pragma unroll
    for (int m = 0; m < 8; ++m) {
#pragma unroll
      for (int n = 0; n < 4; ++n) {
        const int col = nbase + wc * 64 + n * 16 + lm;
        const float bvv = bb[col];
        const int rw0 = M0 + wr * 128 + m * 16 + lq * 4;
        const int bidx = rw0 >> 11, tok = rw0 & 2047;
        bf16x4v pk;
#pragma unroll
        for (int i = 0; i < 4; ++i) pk[i] = (__bf16)(acc[m][n][i] + bvv);
        *(bf16x4v*)(Vtout + ((size_t)(bidx * 2048 + col)) * 2048 + tok) = pk;
      }
    }
  }
}

// ---------- MFMA flash attention v6: KVBLK=32, 3 blocks/CU occupancy --------
// LDS 32KB/block (Ks 2x8KB + Vs 2x8KB); VGPR trimmed (st 16, vreg 8) so the
// register cap allows 3 blocks/CU = 12 waves (was LDS-capped at 2 = 8 waves).
// Same fragment geometry as v5 with the c-loop collapsed (one 32-key subtile).
__global__ __launch_bounds__(256, 3) void attn_mfma(
    const __bf16* __restrict__ Q, const __bf16* __restrict__ K,
    const __bf16* __restrict__ Vt, __bf16* __restrict__ O) {
  __shared__ __attribute__((aligned(16))) char KsL[2][8 * 1024];
  __shared__ __attribute__((aligned(16))) char VsL[2][8 * 1024];

  const int t = threadIdx.x;
  const int w = t >> 6, l = t & 63;
  const int lm = l & 15, quad = l >> 4;
  const int flat = (blockIdx.z * gridDim.y + blockIdx.y) * gridDim.x + blockIdx.x;
  const int swz = (flat & 7) * 64 + (flat >> 3);
  const int b = swz >> 8;
  const int h = (swz >> 4) & 15;
  const int q0 = (swz & 15) * 128;
  const size_t Ds = 2048;
  const size_t hoff = (size_t)h * 128;
  const size_t bbase = (size_t)b * 2048;
  const int sl16 = ((lm << 2) | quad) * 16;
  const float SCL = 0.08838834764831845f * 1.4426950408889634f;

  const int krow = l >> 2, kcol = (l & 3) * 8;
  const int vth = l & 3, vd = l >> 2;

  bf16x8 qf[2][4];
#pragma unroll
  for (int ntq = 0; ntq < 2; ++ntq)
#pragma unroll
    for (int ks = 0; ks < 4; ++ks)
      qf[ntq][ks] = *(const bf16x8*)(Q + (bbase + q0 + w * 32 + ntq * 16 + lm) * Ds + hoff + ks * 32 + quad * 8);

  f32x4 oacc[2][8];
#pragma unroll
  for (int ntq = 0; ntq < 2; ++ntq)
#pragma unroll
    for (int nv = 0; nv < 8; ++nv)
#pragma unroll
      for (int e = 0; e < 4; ++e) oacc[ntq][nv][e] = 0.f;
  float lpart[2] = {0.f, 0.f};

  bf16x8 vreg[2];

  auto loadV = [&](int kt) {
#pragma unroll
    for (int i = 0; i < 2; ++i) {
      const int chunk = w * 2 + i;               // = nv (c collapsed)
      vreg[i] = *(const bf16x8*)(Vt + (bbase + hoff + chunk * 16 + vd) * Ds + kt + vth * 8);
    }
  };
  auto stageK = [&](int kt, char* Kb) {
#pragma unroll
    for (int i = 0; i < 2; ++i) {
      const __bf16* src = K + (bbase + kt + i * 16 + krow) * Ds + hoff + w * 32 + kcol;
      __builtin_amdgcn_global_load_lds(GLB_AS(src), LDS_AS(Kb + (i * 4 + w) * 1024), 16, 0, 0);
    }
  };
  auto writeV = [&](char* Vb) {
    const int s0off = ((vd << 2) | ((vth & 1) * 2)) * 16 + (vth >> 1) * 8;
#pragma unroll
    for (int i = 0; i < 2; ++i) {
      char* base = Vb + (w * 2 + i) * 1024;
      uint4 u = *(const uint4*)&vreg[i];
      *(uint2*)(base + s0off) = make_uint2(u.x, u.y);
      *(uint2*)(base + s0off + 16) = make_uint2(u.z, u.w);
    }
  };

  loadV(0);
  stageK(0, KsL[0]);
  writeV(VsL[0]);

  for (int it = 0; it < 64; ++it) {
    __syncthreads();
    const int cur = it & 1;
    const bool more = (it + 1) < 64;
    if (more) { loadV((it + 1) * 32); stageK((it + 1) * 32, KsL[(it + 1) & 1]); }

    const char* Kb = KsL[cur];
    const char* Vb = VsL[cur];

    // ---- S^T = K Q^T (2 key-16 groups) ----
    f32x4 st[2][2];
#pragma unroll
    for (int mtk = 0; mtk < 2; ++mtk)
#pragma unroll
      for (int ntq = 0; ntq < 2; ++ntq)
#pragma unroll
        for (int e = 0; e < 4; ++e) st[mtk][ntq][e] = 0.f;
    __builtin_amdgcn_s_setprio(1);
#pragma unroll
    for (int ks = 0; ks < 4; ++ks) {
#pragma unroll
      for (int mtk = 0; mtk < 2; ++mtk) {
        bf16x8 kf = *(const bf16x8*)(Kb + (mtk * 4 + ks) * 1024 + sl16);
        st[mtk][0] = __builtin_amdgcn_mfma_f32_16x16x32_bf16(kf, qf[0][ks], st[mtk][0], 0, 0, 0);
        st[mtk][1] = __builtin_amdgcn_mfma_f32_16x16x32_bf16(kf, qf[1][ks], st[mtk][1], 0, 0, 0);
      }
    }
    __builtin_amdgcn_s_setprio(0);

    // ---- P = exp(S*sc); PV ----
    bf16x8 pf[2];
#pragma unroll
    for (int ntq = 0; ntq < 2; ++ntq) {
#pragma unroll
      for (int half = 0; half < 2; ++half) {
        const f32x4 sv = st[half][ntq];
#pragma unroll
        for (int r = 0; r < 4; ++r) {
          const float p = exp2f(sv[r] * SCL);
          const __bf16 pb = (__bf16)p;
          pf[ntq][half * 4 + r] = pb;
          lpart[ntq] += (float)pb;
        }
      }
    }
    __builtin_amdgcn_s_setprio(1);
#pragma unroll
    for (int nv = 0; nv < 8; ++nv) {
      bf16x8 vf = *(const bf16x8*)(Vb + nv * 1024 + sl16);
      oacc[0][nv] = __builtin_amdgcn_mfma_f32_16x16x32_bf16(pf[0], vf, oacc[0][nv], 0, 0, 0);
      oacc[1][nv] = __builtin_amdgcn_mfma_f32_16x16x32_bf16(pf[1], vf, oacc[1][nv], 0, 0, 0);
    }
    __builtin_amdgcn_s_setprio(0);

    if (more) writeV(VsL[(it + 1) & 1]);
  }

  float linv[2];
#pragma unroll
  for (int ntq = 0; ntq < 2; ++ntq) {
    float v = lpart[ntq];
    v += __shfl_xor(v, 16, 64);
    v += __shfl_xor(v, 32, 64);
    linv[ntq] = 1.f / v;
  }
  float oinv[2][4];
#pragma unroll
  for (int ntq = 0; ntq < 2; ++ntq)
#pragma unroll
    for (int r = 0; r < 4; ++r)
      oinv[ntq][r] = __shfl(linv[ntq], quad * 4 + r, 64);

#pragma unroll
  for (int ntq = 0; ntq < 2; ++ntq)
#pragma unroll
    for (int nv = 0; nv < 8; ++nv)
#pragma unroll
      for (int r = 0; r < 4; ++r) {
        const int qrow = q0 + w * 32 + ntq * 16 + quad * 4 + r;
        O[(bbase + qrow) * Ds + hoff + nv * 16 + lm] = (__bf16)(oacc[ntq][nv][r] * oinv[ntq][r]);
      }
}

// ---------- launch ----------
extern "C" void kernel_launch(void* const* d_in, const int* in_sizes, int n_in,
                              void* d_out, int out_size, void* d_ws, size_t ws_size,
                              hipStream_t stream) {
  const float* x      = (const float*)d_in[0];
  const float* Wq     = (const float*)d_in[1];
  const float* bq     = (const float*)d_in[2];
  const float* Wk     = (const float*)d_in[3];
  const float* bk     = (const float*)d_in[4];
  const float* Wv     = (const float*)d_in[5];
  const float* bv     = (const float*)d_in[6];
  const float* Wo     = (const float*)d_in[7];
  const float* bo     = (const float*)d_in[8];
  const float* scale1 = (const float*)d_in[9];
  const float* scale2 = (const float*)d_in[10];
  const float* W1     = (const float*)d_in[11];
  const float* W2     = (const float*)d_in[12];
  const float* W3     = (const float*)d_in[13];

  const int M = 4096, N = 2048, Kd = 2048;
  char* ws = (char*)d_ws;
  const size_t WT_B = (size_t)2048 * 2048 * 2;   // 8 MB
  const size_t ACT_B = (size_t)4096 * 2048 * 2;  // 16 MB
  __bf16* wt[7];
  size_t off = 0;
  for (int i = 0; i < 7; ++i) { wt[i] = (__bf16*)(ws + off); off += WT_B; }
  __bf16* hn1  = (__bf16*)(ws + off); off += ACT_B;
  __bf16* Qb   = (__bf16*)(ws + off); off += ACT_B;
  __bf16* Kb   = (__bf16*)(ws + off); off += ACT_B;
  __bf16* VtG  = (__bf16*)(ws + off); off += ACT_B;
  __bf16* attn = (__bf16*)(ws + off); off += ACT_B;
  __bf16* hn2  = (__bf16*)(ws + off); off += ACT_B;
  __bf16* x1b  = (__bf16*)(ws + off); off += ACT_B;
  __bf16* fmb  = (__bf16*)(ws + off); off += ACT_B;

  dim3 tb(256);
  {
    TP p;
    p.s[0] = Wq; p.s[1] = Wk; p.s[2] = Wv; p.s[3] = Wo; p.s[4] = W1; p.s[5] = W2; p.s[6] = W3;
    for (int i = 0; i < 7; ++i) p.d[i] = wt[i];
    transpose_convert_all<<<dim3(64, 64, 7), tb, 0, stream>>>(p);
  }

  rmsnorm_k<<<4096, tb, 0, stream>>>(x, scale1, hn1);

  gemm_qkv<<<dim3(6144 / 256, M / 256), dim3(512), 0, stream>>>(
      hn1, wt[0], bq, bk, bv, Qb, Kb, VtG, Kd);

  dim3 ag(2048 / 128, 16, 2);
  attn_mfma<<<ag, tb, 0, stream>>>(Qb, Kb, VtG, attn);

  dim3 gg(N / 128, M / 128);
  gemm_bt<true, true, true, false><<<gg, tb, 0, stream>>>(attn, wt[3], bo, x, nullptr, d_out, M, N, Kd);

  rmsnorm_k<<<4096, tb, 0, stream>>>((const float*)d_out, scale2, hn2);

  gemm_bt<false, false, false, false><<<gg, tb, 0, stream>>>(hn2, wt[4], nullptr, nullptr, nullptr, x1b, M, N, Kd);
  gemm_bt<false, false, false, true><<<gg, tb, 0, stream>>>(x1b, wt[5], nullptr, nullptr, x1b, fmb, M, N, Kd);
  gemm_bt<true, false, true, false><<<gg, tb, 0, stream>>>(fmb, wt[6], nullptr, x, nullptr, d_out, M, N, Kd);
}

// Round 6
// 620.704 us; speedup vs baseline: 1.0211x; 1.0128x over previous
//
#include <hip/hip_runtime.h>

// ---------- types ----------
typedef __bf16 bf16x8 __attribute__((ext_vector_type(8)));
typedef __bf16 bf16x4v __attribute__((ext_vector_type(4)));
typedef float  f32x4  __attribute__((ext_vector_type(4)));

#define LDS_AS(p) ((__attribute__((address_space(3))) void*)(p))
#define GLB_AS(p) ((const __attribute__((address_space(1))) void*)(p))

// ---------- batched weight f32 -> bf16 transposed: Wt[n][k] = W[k][n] ----------
struct TP { const float* s[7]; __bf16* d[7]; };
__global__ __launch_bounds__(256) void transpose_convert_all(TP p) {
  const float* __restrict__ W = p.s[blockIdx.z];
  __bf16* __restrict__ Wt = p.d[blockIdx.z];
  __shared__ float tile[32][33];
  const int tx = threadIdx.x & 31, ty = threadIdx.x >> 5;
  const int n0 = blockIdx.x * 32, k0 = blockIdx.y * 32;
#pragma unroll
  for (int j = 0; j < 4; ++j)
    tile[ty + j * 8][tx] = W[(size_t)(k0 + ty + j * 8) * 2048 + n0 + tx];
  __syncthreads();
#pragma unroll
  for (int j = 0; j < 4; ++j)
    Wt[(size_t)(n0 + ty + j * 8) * 2048 + k0 + tx] = (__bf16)tile[tx][ty + j * 8];
}

// ---------- RMSNorm: f32 in -> bf16 out, D=2048, one block per row ----------
__global__ __launch_bounds__(256) void rmsnorm_k(
    const float* __restrict__ x, const float* __restrict__ scale,
    __bf16* __restrict__ out) {
  const int row = blockIdx.x, t = threadIdx.x;
  const float4* xr = (const float4*)(x + (size_t)row * 2048);
  float4 a = xr[t], b2 = xr[t + 256];
  float ss = a.x * a.x + a.y * a.y + a.z * a.z + a.w * a.w +
             b2.x * b2.x + b2.y * b2.y + b2.z * b2.z + b2.w * b2.w;
#pragma unroll
  for (int ofs = 32; ofs; ofs >>= 1) ss += __shfl_xor(ss, ofs, 64);
  __shared__ float red[4];
  if ((t & 63) == 0) red[t >> 6] = ss;
  __syncthreads();
  ss = red[0] + red[1] + red[2] + red[3];
  const float rs = rsqrtf(ss * (1.f / 2048.f) + 1e-5f);
  const float4* sr = (const float4*)scale;
  float4 s1 = sr[t], s2 = sr[t + 256];
  __bf16* orow = out + (size_t)row * 2048;
  orow[t * 4 + 0] = (__bf16)(a.x * rs * s1.x);
  orow[t * 4 + 1] = (__bf16)(a.y * rs * s1.y);
  orow[t * 4 + 2] = (__bf16)(a.z * rs * s1.z);
  orow[t * 4 + 3] = (__bf16)(a.w * rs * s1.w);
  orow[(t + 256) * 4 + 0] = (__bf16)(b2.x * rs * s2.x);
  orow[(t + 256) * 4 + 1] = (__bf16)(b2.y * rs * s2.y);
  orow[(t + 256) * 4 + 2] = (__bf16)(b2.z * rs * s2.z);
  orow[(t + 256) * 4 + 3] = (__bf16)(b2.w * rs * s2.w);
}

// ---------- GEMM: C[M,N] = A[M,K] @ Bt[N,K]^T, dbuf single-barrier (128^2) ----
// + T1 XCD-chunked swizzle (512 blocks at all call sites, 512%8==0).
// VTRANS: write C transposed as Vt[(b*2048+col)][token] bf16x4-packed (+bias).
template <bool OUTF32, bool HASBIAS, bool HASRES, bool SILU, bool VTRANS = false>
__global__ __launch_bounds__(256) void gemm_bt(
    const __bf16* __restrict__ A, const __bf16* __restrict__ Bt,
    const float* __restrict__ bias, const float* __restrict__ res,
    const __bf16* __restrict__ ew, void* __restrict__ Cout,
    int M, int N, int Kd) {
  __shared__ __attribute__((aligned(16))) __bf16 As[2][128 * 32];
  __shared__ __attribute__((aligned(16))) __bf16 Bs[2][128 * 32];
  const int tid = threadIdx.x;
  const int w = tid >> 6, l = tid & 63;
  const int flat = blockIdx.y * gridDim.x + blockIdx.x;
  const int nwg = gridDim.x * gridDim.y;          // 512 at all call sites
  const int swz = (flat & 7) * (nwg >> 3) + (flat >> 3);
  const int bx = swz % gridDim.x, by = swz / gridDim.x;
  const int M0 = by * 128, N0 = bx * 128;
  const int wr = w >> 1, wc = w & 1;
  const int lm = l & 15, lq = l >> 4;

  f32x4 acc[4][4];
#pragma unroll
  for (int mt = 0; mt < 4; ++mt)
#pragma unroll
    for (int nt = 0; nt < 4; ++nt)
#pragma unroll
      for (int e = 0; e < 4; ++e) acc[mt][nt][e] = 0.f;

  const int offA0 = (w * 2 + 0) * 1024 + l * 16;
  const int offA1 = (w * 2 + 1) * 1024 + l * 16;
  const int row0 = offA0 >> 6, kb0 = offA0 & 63;
  const int row1 = offA1 >> 6, kb1 = offA1 & 63;
  const int nIt = Kd >> 5;

  auto stage = [&](int k0, int bsel) {
    const char* ga0 = (const char*)(A + (size_t)(M0 + row0) * Kd + k0) + kb0;
    const char* ga1 = (const char*)(A + (size_t)(M0 + row1) * Kd + k0) + kb1;
    const char* gb0 = (const char*)(Bt + (size_t)(N0 + row0) * Kd + k0) + kb0;
    const char* gb1 = (const char*)(Bt + (size_t)(N0 + row1) * Kd + k0) + kb1;
    __builtin_amdgcn_global_load_lds(GLB_AS(ga0), LDS_AS(((char*)As[bsel]) + (w * 2 + 0) * 1024), 16, 0, 0);
    __builtin_amdgcn_global_load_lds(GLB_AS(ga1), LDS_AS(((char*)As[bsel]) + (w * 2 + 1) * 1024), 16, 0, 0);
    __builtin_amdgcn_global_load_lds(GLB_AS(gb0), LDS_AS(((char*)Bs[bsel]) + (w * 2 + 0) * 1024), 16, 0, 0);
    __builtin_amdgcn_global_load_lds(GLB_AS(gb1), LDS_AS(((char*)Bs[bsel]) + (w * 2 + 1) * 1024), 16, 0, 0);
  };

  stage(0, 0);
  for (int it = 0; it < nIt; ++it) {
    __syncthreads();
    if (it + 1 < nIt) stage((it + 1) * 32, (it + 1) & 1);
    const __bf16* Ab = As[it & 1];
    const __bf16* Bb = Bs[it & 1];
    bf16x8 af[4], bfr[4];
#pragma unroll
    for (int mt = 0; mt < 4; ++mt)
      af[mt] = *(const bf16x8*)(Ab + (wr * 64 + mt * 16 + lm) * 32 + lq * 8);
#pragma unroll
    for (int nt = 0; nt < 4; ++nt)
      bfr[nt] = *(const bf16x8*)(Bb + (wc * 64 + nt * 16 + lm) * 32 + lq * 8);
#pragma unroll
    for (int mt = 0; mt < 4; ++mt)
#pragma unroll
      for (int nt = 0; nt < 4; ++nt)
        acc[mt][nt] = __builtin_amdgcn_mfma_f32_16x16x32_bf16(af[mt], bfr[nt], acc[mt][nt], 0, 0, 0);
  }

  const int lr = lq * 4;
#pragma unroll
  for (int mt = 0; mt < 4; ++mt) {
#pragma unroll
    for (int nt = 0; nt < 4; ++nt) {
      const int col = N0 + wc * 64 + nt * 16 + lm;
      float bv = 0.f;
      if (HASBIAS) bv = bias[col];
      if (VTRANS) {
        const int rw0 = M0 + wr * 64 + mt * 16 + lr;
        const int bidx = rw0 >> 11, tok = rw0 & 2047;
        bf16x4v pk;
#pragma unroll
        for (int i = 0; i < 4; ++i) pk[i] = (__bf16)(acc[mt][nt][i] + bv);
        *(bf16x4v*)((__bf16*)Cout + ((size_t)(bidx * 2048 + col)) * 2048 + tok) = pk;
      } else {
#pragma unroll
        for (int i = 0; i < 4; ++i) {
          const int row = M0 + wr * 64 + mt * 16 + lr + i;
          const size_t off = (size_t)row * N + col;
          float v = acc[mt][nt][i] + bv;
          if (HASRES) v += res[off];
          if (SILU) {
            const float x1v = (float)ew[off];
            v = x1v * (1.f / (1.f + __expf(-x1v))) * v;
          }
          if (OUTF32) ((float*)Cout)[off] = v;
          else ((__bf16*)Cout)[off] = (__bf16)v;
        }
      }
    }
  }
}

// ---------- fused QK GEMM: 256^2 tile, BK=64, 8 waves, 8-phase counted-vmcnt ----
// Now covers ONLY Q,K (N 0..4095): grid 16x16 = 256 blocks = one perfect
// dispatch round (was 384 blocks = 1.5 rounds, 2T makespan). V is a separate
// 128^2 gemm_bt<VTRANS> launch (512 blocks = 2 perfect rounds).
__global__ __launch_bounds__(512, 2) void gemm_qkv(
    const __bf16* __restrict__ A, const __bf16* __restrict__ Bt,
    const float* __restrict__ bq, const float* __restrict__ bk,
    __bf16* __restrict__ Qout, __bf16* __restrict__ Kout, int Kd) {
  __shared__ __attribute__((aligned(16))) char lds[2][4][16384];

  const int tid = threadIdx.x;
  const int w = tid >> 6, l = tid & 63;
  const int wr = w >> 2, wc = w & 3;
  const int lm = l & 15, lq = l >> 4;

  // XCD-bijective chunked swizzle for nwg=256: each XCD gets 32 consecutive
  // swz = 2 N-panels (2x256x2048x2B = 2MB B-weights, L2-resident) x 16 M.
  const int flat = blockIdx.y * 16 + blockIdx.x;
  const int swz = (flat & 7) * 32 + (flat >> 3);
  const int bx = swz >> 4, by = swz & 15;
  const int N0 = bx * 256, M0 = by * 256;

  const int srow = w * 8 + (l >> 3);
  const int scol = ((l & 7) ^ (l >> 3)) * 8;
  const __bf16* aS = A + (size_t)(M0 + srow) * Kd + scol;
  const __bf16* bS = Bt + (size_t)(N0 + srow) * Kd + scol;

  auto stageHT = [&](int t, int s, int db) {
    char* dst = lds[db][s] + w * 1024;
    const __bf16* src = (s >= 2) ? (aS + (size_t)(s - 2) * 128 * Kd + t * 64)
                                 : (bS + (size_t)s * 128 * Kd + t * 64);
    __builtin_amdgcn_global_load_lds(GLB_AS(src), LDS_AS(dst), 16, 0, 0);
    __builtin_amdgcn_global_load_lds(GLB_AS(src + (size_t)64 * Kd), LDS_AS(dst + 8192), 16, 0, 0);
  };

  f32x4 acc[8][4];
#pragma unroll
  for (int m = 0; m < 8; ++m)
#pragma unroll
    for (int n = 0; n < 4; ++n)
#pragma unroll
      for (int e = 0; e < 4; ++e) acc[m][n][e] = 0.f;

  const int swzr = (lm & 7) << 4;
  const int c0 = (lq * 16) ^ swzr;
  const int c1 = ((64 + lq * 16)) ^ swzr;
  const int arow = lm * 128;
  const int brow = ((wc & 1) * 64 + lm) * 128;

  stageHT(0, 0, 0); stageHT(0, 1, 0); stageHT(0, 2, 0); stageHT(0, 3, 0);
  stageHT(1, 0, 1); stageHT(1, 1, 1); stageHT(1, 2, 1);
  asm volatile("s_waitcnt vmcnt(6)" ::: "memory");
  __builtin_amdgcn_s_barrier();

  const int NT = Kd >> 6;
  bf16x8 af[4][2], bfr[4][2];

#define BAR()                                            \
  do {                                                   \
    asm volatile("" ::: "memory");                       \
    __builtin_amdgcn_s_barrier();                        \
    asm volatile("" ::: "memory");                       \
  } while (0)

#define MFMA_QUAD(MB, NB)                                                          \
  do {                                                                             \
    _Pragma("unroll") for (int m = 0; m < 4; ++m)                                  \
      _Pragma("unroll") for (int n = 0; n < 2; ++n) {                              \
        acc[(MB) + m][(NB) + n] = __builtin_amdgcn_mfma_f32_16x16x32_bf16(         \
            af[m][0], bfr[(NB) + n][0], acc[(MB) + m][(NB) + n], 0, 0, 0);         \
        acc[(MB) + m][(NB) + n] = __builtin_amdgcn_mfma_f32_16x16x32_bf16(         \
            af[m][1], bfr[(NB) + n][1], acc[(MB) + m][(NB) + n], 0, 0, 0);         \
      }                                                                            \
  } while (0)

#define TILE_BODY(T, BUF)                                                       \
  do {                                                                          \
    const char* Ab = lds[BUF][2 + wr];                                          \
    const char* Bb = lds[BUF][wc >> 1];                                         \
    _Pragma("unroll") for (int m = 0; m < 4; ++m) {                             \
      af[m][0] = *(const bf16x8*)(Ab + arow + m * 2048 + c0);                   \
      af[m][1] = *(const bf16x8*)(Ab + arow + m * 2048 + c1);                   \
    }                                                                           \
    _Pragma("unroll") for (int n = 0; n < 4; ++n) {                             \
      bfr[n][0] = *(const bf16x8*)(Bb + brow + n * 2048 + c0);                  \
      bfr[n][1] = *(const bf16x8*)(Bb + brow + n * 2048 + c1);                  \
    }                                                                           \
    if ((T) + 1 < NT) stageHT((T) + 1, 3, (BUF) ^ 1);                           \
    BAR();                                                                      \
    __builtin_amdgcn_s_setprio(1);                                              \
    MFMA_QUAD(0, 0);                                                            \
    __builtin_amdgcn_s_setprio(0);                                              \
    asm volatile("s_waitcnt lgkmcnt(0)" ::: "memory");                          \
    BAR();                                                                      \
    if ((T) + 2 < NT) stageHT((T) + 2, 0, BUF);                                 \
    BAR();                                                                      \
    __builtin_amdgcn_s_setprio(1);                                              \
    MFMA_QUAD(0, 2);                                                            \
    __builtin_amdgcn_s_setprio(0);                                              \
    BAR();                                                                      \
    _Pragma("unroll") for (int m = 0; m < 4; ++m) {                             \
      af[m][0] = *(const bf16x8*)(Ab + arow + (m + 4) * 2048 + c0);             \
      af[m][1] = *(const bf16x8*)(Ab + arow + (m + 4) * 2048 + c1);             \
    }                                                                           \
    if ((T) + 2 < NT) stageHT((T) + 2, 1, BUF);                                 \
    BAR();                                                                      \
    __builtin_amdgcn_s_setprio(1);                                              \
    MFMA_QUAD(4, 0);                                                            \
    __builtin_amdgcn_s_setprio(0);                                              \
    asm volatile("s_waitcnt lgkmcnt(0)" ::: "memory");                          \
    BAR();                                                                      \
    if ((T) + 2 < NT) stageHT((T) + 2, 2, BUF);                                 \
    BAR();                                                                      \
    __builtin_amdgcn_s_setprio(1);                                              \
    MFMA_QUAD(4, 2);                                                            \
    __builtin_amdgcn_s_setprio(0);                                              \
    if ((T) + 2 < NT) { asm volatile("s_waitcnt vmcnt(6)" ::: "memory"); }      \
    else { asm volatile("s_waitcnt vmcnt(0)" ::: "memory"); }                   \
    BAR();                                                                      \
  } while (0)

  for (int tp = 0; tp < NT; tp += 2) {
    TILE_BODY(tp, 0);
    TILE_BODY(tp + 1, 1);
  }
#undef TILE_BODY
#undef MFMA_QUAD
#undef BAR

  const int seg = N0 >> 11;               // 0:Q 1:K
  const int nbase = N0 & 2047;
  const float* bb = (seg == 0) ? bq : bk;
  __bf16* dst = (seg == 0) ? Qout : Kout;
#pragma unroll
  for (int m = 0; m < 8; ++m) {
#pragma unroll
    for (int n = 0; n < 4; ++n) {
      const int col = nbase + wc * 64 + n * 16 + lm;
      const float bvv = bb[col];
#pragma unroll
      for (int i = 0; i < 4; ++i) {
        const int row = M0 + wr * 128 + m * 16 + lq * 4 + i;
        dst[(size_t)row * 2048 + col] = (__bf16)(acc[m][n][i] + bvv);
      }
    }
  }
}

// ---------- MFMA flash attention v5 + T5 setprio + XCD-chunked swizzle -------
// (round-3 body restored: KVBLK=64 measured ~8us faster than KVBLK=32 v6)
__global__ __launch_bounds__(256, 2) void attn_mfma(
    const __bf16* __restrict__ Q, const __bf16* __restrict__ K,
    const __bf16* __restrict__ Vt, __bf16* __restrict__ O) {
  __shared__ __attribute__((aligned(16))) char KsL[2][16 * 1024];
  __shared__ __attribute__((aligned(16))) char VsL[2][16 * 1024];

  const int t = threadIdx.x;
  const int w = t >> 6, l = t & 63;
  const int lm = l & 15, quad = l >> 4;
  const int flat = (blockIdx.z * gridDim.y + blockIdx.y) * gridDim.x + blockIdx.x;
  const int swz = (flat & 7) * 64 + (flat >> 3);
  const int b = swz >> 8;
  const int h = (swz >> 4) & 15;
  const int q0 = (swz & 15) * 128;
  const size_t Ds = 2048;
  const size_t hoff = (size_t)h * 128;
  const size_t bbase = (size_t)b * 2048;
  const int sl16 = ((lm << 2) | quad) * 16;
  const float SCL = 0.08838834764831845f * 1.4426950408889634f;

  const int krow = l >> 2, kcol = (l & 3) * 8;
  const int vth = l & 3, vd = l >> 2;

  bf16x8 qf[2][4];
#pragma unroll
  for (int ntq = 0; ntq < 2; ++ntq)
#pragma unroll
    for (int ks = 0; ks < 4; ++ks)
      qf[ntq][ks] = *(const bf16x8*)(Q + (bbase + q0 + w * 32 + ntq * 16 + lm) * Ds + hoff + ks * 32 + quad * 8);

  f32x4 oacc[2][8];
#pragma unroll
  for (int ntq = 0; ntq < 2; ++ntq)
#pragma unroll
    for (int nv = 0; nv < 8; ++nv)
#pragma unroll
      for (int e = 0; e < 4; ++e) oacc[ntq][nv][e] = 0.f;
  float lpart[2] = {0.f, 0.f};

  bf16x8 vreg[4];

  auto loadV = [&](int kt) {
#pragma unroll
    for (int i = 0; i < 4; ++i) {
      const int chunk = w * 4 + i;
      const int nv = chunk >> 1, c = chunk & 1;
      vreg[i] = *(const bf16x8*)(Vt + (bbase + hoff + nv * 16 + vd) * Ds + kt + c * 32 + vth * 8);
    }
  };
  auto stageK = [&](int kt, char* Kb) {
#pragma unroll
    for (int i = 0; i < 4; ++i) {
      const __bf16* src = K + (bbase + kt + i * 16 + krow) * Ds + hoff + w * 32 + kcol;
      __builtin_amdgcn_global_load_lds(GLB_AS(src), LDS_AS(Kb + (i * 4 + w) * 1024), 16, 0, 0);
    }
  };
  auto writeV = [&](char* Vb) {
    const int s0off = ((vd << 2) | ((vth & 1) * 2)) * 16 + (vth >> 1) * 8;
#pragma unroll
    for (int i = 0; i < 4; ++i) {
      char* base = Vb + (w * 4 + i) * 1024;
      uint4 u = *(const uint4*)&vreg[i];
      *(uint2*)(base + s0off) = make_uint2(u.x, u.y);
      *(uint2*)(base + s0off + 16) = make_uint2(u.z, u.w);
    }
  };

  loadV(0);
  stageK(0, KsL[0]);
  writeV(VsL[0]);

  for (int it = 0; it < 32; ++it) {
    __syncthreads();
    const int cur = it & 1;
    const bool more = (it + 1) < 32;
    if (more) { loadV((it + 1) * 64); stageK((it + 1) * 64, KsL[(it + 1) & 1]); }

    const char* Kb = KsL[cur];
    const char* Vb = VsL[cur];

    f32x4 st[4][2];
#pragma unroll
    for (int mtk = 0; mtk < 4; ++mtk)
#pragma unroll
      for (int ntq = 0; ntq < 2; ++ntq)
#pragma unroll
        for (int e = 0; e < 4; ++e) st[mtk][ntq][e] = 0.f;
    __builtin_amdgcn_s_setprio(1);
#pragma unroll
    for (int ks = 0; ks < 4; ++ks) {
#pragma unroll
      for (int mtk = 0; mtk < 4; ++mtk) {
        bf16x8 kf = *(const bf16x8*)(Kb + (mtk * 4 + ks) * 1024 + sl16);
        st[mtk][0] = __builtin_amdgcn_mfma_f32_16x16x32_bf16(kf, qf[0][ks], st[mtk][0], 0, 0, 0);
        st[mtk][1] = __builtin_amdgcn_mfma_f32_16x16x32_bf16(kf, qf[1][ks], st[mtk][1], 0, 0, 0);
      }
    }
    __builtin_amdgcn_s_setprio(0);

#pragma unroll
    for (int c = 0; c < 2; ++c) {
      bf16x8 pf[2];
#pragma unroll
      for (int ntq = 0; ntq < 2; ++ntq) {
#pragma unroll
        for (int half = 0; half < 2; ++half) {
          const f32x4 sv = st[c * 2 + half][ntq];
#pragma unroll
          for (int r = 0; r < 4; ++r) {
            const float p = exp2f(sv[r] * SCL);
            const __bf16 pb = (__bf16)p;
            pf[ntq][half * 4 + r] = pb;
            lpart[ntq] += (float)pb;
          }
        }
      }
      __builtin_amdgcn_s_setprio(1);
#pragma unroll
      for (int nv = 0; nv < 8; ++nv) {
        bf16x8 vf = *(const bf16x8*)(Vb + (nv * 2 + c) * 1024 + sl16);
        oacc[0][nv] = __builtin_amdgcn_mfma_f32_16x16x32_bf16(pf[0], vf, oacc[0][nv], 0, 0, 0);
        oacc[1][nv] = __builtin_amdgcn_mfma_f32_16x16x32_bf16(pf[1], vf, oacc[1][nv], 0, 0, 0);
      }
      __builtin_amdgcn_s_setprio(0);
    }

    if (more) writeV(VsL[(it + 1) & 1]);
  }

  float linv[2];
#pragma unroll
  for (int ntq = 0; ntq < 2; ++ntq) {
    float v = lpart[ntq];
    v += __shfl_xor(v, 16, 64);
    v += __shfl_xor(v, 32, 64);
    linv[ntq] = 1.f / v;
  }
  float oinv[2][4];
#pragma unroll
  for (int ntq = 0; ntq < 2; ++ntq)
#pragma unroll
    for (int r = 0; r < 4; ++r)
      oinv[ntq][r] = __shfl(linv[ntq], quad * 4 + r, 64);

#pragma unroll
  for (int ntq = 0; ntq < 2; ++ntq)
#pragma unroll
    for (int nv = 0; nv < 8; ++nv)
#pragma unroll
      for (int r = 0; r < 4; ++r) {
        const int qrow = q0 + w * 32 + ntq * 16 + quad * 4 + r;
        O[(bbase + qrow) * Ds + hoff + nv * 16 + lm] = (__bf16)(oacc[ntq][nv][r] * oinv[ntq][r]);
      }
}

// ---------- launch ----------
extern "C" void kernel_launch(void* const* d_in, const int* in_sizes, int n_in,
                              void* d_out, int out_size, void* d_ws, size_t ws_size,
                              hipStream_t stream) {
  const float* x      = (const float*)d_in[0];
  const float* Wq     = (const float*)d_in[1];
  const float* bq     = (const float*)d_in[2];
  const float* Wk     = (const float*)d_in[3];
  const float* bk     = (const float*)d_in[4];
  const float* Wv     = (const float*)d_in[5];
  const float* bv     = (const float*)d_in[6];
  const float* Wo     = (const float*)d_in[7];
  const float* bo     = (const float*)d_in[8];
  const float* scale1 = (const float*)d_in[9];
  const float* scale2 = (const float*)d_in[10];
  const float* W1     = (const float*)d_in[11];
  const float* W2     = (const float*)d_in[12];
  const float* W3     = (const float*)d_in[13];

  const int M = 4096, N = 2048, Kd = 2048;
  char* ws = (char*)d_ws;
  const size_t WT_B = (size_t)2048 * 2048 * 2;   // 8 MB
  const size_t ACT_B = (size_t)4096 * 2048 * 2;  // 16 MB
  __bf16* wt[7];
  size_t off = 0;
  for (int i = 0; i < 7; ++i) { wt[i] = (__bf16*)(ws + off); off += WT_B; }
  __bf16* hn1  = (__bf16*)(ws + off); off += ACT_B;
  __bf16* Qb   = (__bf16*)(ws + off); off += ACT_B;
  __bf16* Kb   = (__bf16*)(ws + off); off += ACT_B;
  __bf16* VtG  = (__bf16*)(ws + off); off += ACT_B;
  __bf16* attn = (__bf16*)(ws + off); off += ACT_B;
  __bf16* hn2  = (__bf16*)(ws + off); off += ACT_B;
  __bf16* x1b  = (__bf16*)(ws + off); off += ACT_B;
  __bf16* fmb  = (__bf16*)(ws + off); off += ACT_B;

  dim3 tb(256);
  {
    TP p;
    p.s[0] = Wq; p.s[1] = Wk; p.s[2] = Wv; p.s[3] = Wo; p.s[4] = W1; p.s[5] = W2; p.s[6] = W3;
    for (int i = 0; i < 7; ++i) p.d[i] = wt[i];
    transpose_convert_all<<<dim3(64, 64, 7), tb, 0, stream>>>(p);
  }

  rmsnorm_k<<<4096, tb, 0, stream>>>(x, scale1, hn1);

  // QK GEMM: 256^2 8-phase over N 0..4095, 256 blocks = 1 perfect round
  gemm_qkv<<<dim3(16, 16), dim3(512), 0, stream>>>(hn1, wt[0], bq, bk, Qb, Kb, Kd);
  // V GEMM: 128^2 structure, transposed epilogue, 512 blocks = 2 perfect rounds
  gemm_bt<false, true, false, false, true><<<dim3(16, 32), tb, 0, stream>>>(
      hn1, wt[2], bv, nullptr, nullptr, VtG, M, 2048, Kd);

  dim3 ag(2048 / 128, 16, 2);
  attn_mfma<<<ag, tb, 0, stream>>>(Qb, Kb, VtG, attn);

  dim3 gg(N / 128, M / 128);
  gemm_bt<true, true, true, false><<<gg, tb, 0, stream>>>(attn, wt[3], bo, x, nullptr, d_out, M, N, Kd);

  rmsnorm_k<<<4096, tb, 0, stream>>>((const float*)d_out, scale2, hn2);

  gemm_bt<false, false, false, false><<<gg, tb, 0, stream>>>(hn2, wt[4], nullptr, nullptr, nullptr, x1b, M, N, Kd);
  gemm_bt<false, false, false, true><<<gg, tb, 0, stream>>>(x1b, wt[5], nullptr, nullptr, x1b, fmb, M, N, Kd);
  gemm_bt<true, false, true, false><<<gg, tb, 0, stream>>>(fmb, wt[6], nullptr, x, nullptr, d_out, M, N, Kd);
}

// Round 7
// 612.133 us; speedup vs baseline: 1.0354x; 1.0140x over previous
//
#include <hip/hip_runtime.h>

// ---------- types ----------
typedef __bf16 bf16x8 __attribute__((ext_vector_type(8)));
typedef __bf16 bf16x4v __attribute__((ext_vector_type(4)));
typedef float  f32x4  __attribute__((ext_vector_type(4)));

#define LDS_AS(p) ((__attribute__((address_space(3))) void*)(p))
#define GLB_AS(p) ((const __attribute__((address_space(1))) void*)(p))

// ---------- batched weight f32 -> bf16 transposed: Wt[n][k] = W[k][n] ----------
struct TP { const float* s[7]; __bf16* d[7]; };
__global__ __launch_bounds__(256) void transpose_convert_all(TP p) {
  const float* __restrict__ W = p.s[blockIdx.z];
  __bf16* __restrict__ Wt = p.d[blockIdx.z];
  __shared__ float tile[32][33];
  const int tx = threadIdx.x & 31, ty = threadIdx.x >> 5;
  const int n0 = blockIdx.x * 32, k0 = blockIdx.y * 32;
#pragma unroll
  for (int j = 0; j < 4; ++j)
    tile[ty + j * 8][tx] = W[(size_t)(k0 + ty + j * 8) * 2048 + n0 + tx];
  __syncthreads();
#pragma unroll
  for (int j = 0; j < 4; ++j)
    Wt[(size_t)(n0 + ty + j * 8) * 2048 + k0 + tx] = (__bf16)tile[tx][ty + j * 8];
}

// ---------- RMSNorm: f32 in -> bf16 out, D=2048, one block per row ----------
__global__ __launch_bounds__(256) void rmsnorm_k(
    const float* __restrict__ x, const float* __restrict__ scale,
    __bf16* __restrict__ out) {
  const int row = blockIdx.x, t = threadIdx.x;
  const float4* xr = (const float4*)(x + (size_t)row * 2048);
  float4 a = xr[t], b2 = xr[t + 256];
  float ss = a.x * a.x + a.y * a.y + a.z * a.z + a.w * a.w +
             b2.x * b2.x + b2.y * b2.y + b2.z * b2.z + b2.w * b2.w;
#pragma unroll
  for (int ofs = 32; ofs; ofs >>= 1) ss += __shfl_xor(ss, ofs, 64);
  __shared__ float red[4];
  if ((t & 63) == 0) red[t >> 6] = ss;
  __syncthreads();
  ss = red[0] + red[1] + red[2] + red[3];
  const float rs = rsqrtf(ss * (1.f / 2048.f) + 1e-5f);
  const float4* sr = (const float4*)scale;
  float4 s1 = sr[t], s2 = sr[t + 256];
  __bf16* orow = out + (size_t)row * 2048;
  orow[t * 4 + 0] = (__bf16)(a.x * rs * s1.x);
  orow[t * 4 + 1] = (__bf16)(a.y * rs * s1.y);
  orow[t * 4 + 2] = (__bf16)(a.z * rs * s1.z);
  orow[t * 4 + 3] = (__bf16)(a.w * rs * s1.w);
  orow[(t + 256) * 4 + 0] = (__bf16)(b2.x * rs * s2.x);
  orow[(t + 256) * 4 + 1] = (__bf16)(b2.y * rs * s2.y);
  orow[(t + 256) * 4 + 2] = (__bf16)(b2.z * rs * s2.z);
  orow[(t + 256) * 4 + 3] = (__bf16)(b2.w * rs * s2.w);
}

// ---------- GEMM: C[M,N] = A[M,K] @ Bt[N,K]^T, dbuf single-barrier (128^2) ----
// + T1 XCD-chunked swizzle (512 blocks at all call sites, 512%8==0).
// VTRANS: write C transposed as Vt[(b*2048+col)][token] bf16x4-packed (+bias).
template <bool OUTF32, bool HASBIAS, bool HASRES, bool SILU, bool VTRANS = false>
__global__ __launch_bounds__(256) void gemm_bt(
    const __bf16* __restrict__ A, const __bf16* __restrict__ Bt,
    const float* __restrict__ bias, const float* __restrict__ res,
    const __bf16* __restrict__ ew, void* __restrict__ Cout,
    int M, int N, int Kd) {
  __shared__ __attribute__((aligned(16))) __bf16 As[2][128 * 32];
  __shared__ __attribute__((aligned(16))) __bf16 Bs[2][128 * 32];
  const int tid = threadIdx.x;
  const int w = tid >> 6, l = tid & 63;
  const int flat = blockIdx.y * gridDim.x + blockIdx.x;
  const int nwg = gridDim.x * gridDim.y;          // 512 at all call sites
  const int swz = (flat & 7) * (nwg >> 3) + (flat >> 3);
  const int bx = swz % gridDim.x, by = swz / gridDim.x;
  const int M0 = by * 128, N0 = bx * 128;
  const int wr = w >> 1, wc = w & 1;
  const int lm = l & 15, lq = l >> 4;

  f32x4 acc[4][4];
#pragma unroll
  for (int mt = 0; mt < 4; ++mt)
#pragma unroll
    for (int nt = 0; nt < 4; ++nt)
#pragma unroll
      for (int e = 0; e < 4; ++e) acc[mt][nt][e] = 0.f;

  const int offA0 = (w * 2 + 0) * 1024 + l * 16;
  const int offA1 = (w * 2 + 1) * 1024 + l * 16;
  const int row0 = offA0 >> 6, kb0 = offA0 & 63;
  const int row1 = offA1 >> 6, kb1 = offA1 & 63;
  const int nIt = Kd >> 5;

  auto stage = [&](int k0, int bsel) {
    const char* ga0 = (const char*)(A + (size_t)(M0 + row0) * Kd + k0) + kb0;
    const char* ga1 = (const char*)(A + (size_t)(M0 + row1) * Kd + k0) + kb1;
    const char* gb0 = (const char*)(Bt + (size_t)(N0 + row0) * Kd + k0) + kb0;
    const char* gb1 = (const char*)(Bt + (size_t)(N0 + row1) * Kd + k0) + kb1;
    __builtin_amdgcn_global_load_lds(GLB_AS(ga0), LDS_AS(((char*)As[bsel]) + (w * 2 + 0) * 1024), 16, 0, 0);
    __builtin_amdgcn_global_load_lds(GLB_AS(ga1), LDS_AS(((char*)As[bsel]) + (w * 2 + 1) * 1024), 16, 0, 0);
    __builtin_amdgcn_global_load_lds(GLB_AS(gb0), LDS_AS(((char*)Bs[bsel]) + (w * 2 + 0) * 1024), 16, 0, 0);
    __builtin_amdgcn_global_load_lds(GLB_AS(gb1), LDS_AS(((char*)Bs[bsel]) + (w * 2 + 1) * 1024), 16, 0, 0);
  };

  stage(0, 0);
  for (int it = 0; it < nIt; ++it) {
    __syncthreads();
    if (it + 1 < nIt) stage((it + 1) * 32, (it + 1) & 1);
    const __bf16* Ab = As[it & 1];
    const __bf16* Bb = Bs[it & 1];
    bf16x8 af[4], bfr[4];
#pragma unroll
    for (int mt = 0; mt < 4; ++mt)
      af[mt] = *(const bf16x8*)(Ab + (wr * 64 + mt * 16 + lm) * 32 + lq * 8);
#pragma unroll
    for (int nt = 0; nt < 4; ++nt)
      bfr[nt] = *(const bf16x8*)(Bb + (wc * 64 + nt * 16 + lm) * 32 + lq * 8);
#pragma unroll
    for (int mt = 0; mt < 4; ++mt)
#pragma unroll
      for (int nt = 0; nt < 4; ++nt)
        acc[mt][nt] = __builtin_amdgcn_mfma_f32_16x16x32_bf16(af[mt], bfr[nt], acc[mt][nt], 0, 0, 0);
  }

  const int lr = lq * 4;
#pragma unroll
  for (int mt = 0; mt < 4; ++mt) {
#pragma unroll
    for (int nt = 0; nt < 4; ++nt) {
      const int col = N0 + wc * 64 + nt * 16 + lm;
      float bv = 0.f;
      if (HASBIAS) bv = bias[col];
      if (VTRANS) {
        const int rw0 = M0 + wr * 64 + mt * 16 + lr;
        const int bidx = rw0 >> 11, tok = rw0 & 2047;
        bf16x4v pk;
#pragma unroll
        for (int i = 0; i < 4; ++i) pk[i] = (__bf16)(acc[mt][nt][i] + bv);
        *(bf16x4v*)((__bf16*)Cout + ((size_t)(bidx * 2048 + col)) * 2048 + tok) = pk;
      } else {
#pragma unroll
        for (int i = 0; i < 4; ++i) {
          const int row = M0 + wr * 64 + mt * 16 + lr + i;
          const size_t off = (size_t)row * N + col;
          float v = acc[mt][nt][i] + bv;
          if (HASRES) v += res[off];
          if (SILU) {
            const float x1v = (float)ew[off];
            v = x1v * (1.f / (1.f + __expf(-x1v))) * v;
          }
          if (OUTF32) ((float*)Cout)[off] = v;
          else ((__bf16*)Cout)[off] = (__bf16)v;
        }
      }
    }
  }
}

// ---------- fused QK GEMM: 256^2 tile, BK=64, 8 waves, 8-phase counted-vmcnt ----
// Covers ONLY Q,K (N 0..4095): grid 16x16 = 256 blocks = one perfect round.
__global__ __launch_bounds__(512, 2) void gemm_qkv(
    const __bf16* __restrict__ A, const __bf16* __restrict__ Bt,
    const float* __restrict__ bq, const float* __restrict__ bk,
    __bf16* __restrict__ Qout, __bf16* __restrict__ Kout, int Kd) {
  __shared__ __attribute__((aligned(16))) char lds[2][4][16384];

  const int tid = threadIdx.x;
  const int w = tid >> 6, l = tid & 63;
  const int wr = w >> 2, wc = w & 3;
  const int lm = l & 15, lq = l >> 4;

  const int flat = blockIdx.y * 16 + blockIdx.x;
  const int swz = (flat & 7) * 32 + (flat >> 3);
  const int bx = swz >> 4, by = swz & 15;
  const int N0 = bx * 256, M0 = by * 256;

  const int srow = w * 8 + (l >> 3);
  const int scol = ((l & 7) ^ (l >> 3)) * 8;
  const __bf16* aS = A + (size_t)(M0 + srow) * Kd + scol;
  const __bf16* bS = Bt + (size_t)(N0 + srow) * Kd + scol;

  auto stageHT = [&](int t, int s, int db) {
    char* dst = lds[db][s] + w * 1024;
    const __bf16* src = (s >= 2) ? (aS + (size_t)(s - 2) * 128 * Kd + t * 64)
                                 : (bS + (size_t)s * 128 * Kd + t * 64);
    __builtin_amdgcn_global_load_lds(GLB_AS(src), LDS_AS(dst), 16, 0, 0);
    __builtin_amdgcn_global_load_lds(GLB_AS(src + (size_t)64 * Kd), LDS_AS(dst + 8192), 16, 0, 0);
  };

  f32x4 acc[8][4];
#pragma unroll
  for (int m = 0; m < 8; ++m)
#pragma unroll
    for (int n = 0; n < 4; ++n)
#pragma unroll
      for (int e = 0; e < 4; ++e) acc[m][n][e] = 0.f;

  const int swzr = (lm & 7) << 4;
  const int c0 = (lq * 16) ^ swzr;
  const int c1 = ((64 + lq * 16)) ^ swzr;
  const int arow = lm * 128;
  const int brow = ((wc & 1) * 64 + lm) * 128;

  stageHT(0, 0, 0); stageHT(0, 1, 0); stageHT(0, 2, 0); stageHT(0, 3, 0);
  stageHT(1, 0, 1); stageHT(1, 1, 1); stageHT(1, 2, 1);
  asm volatile("s_waitcnt vmcnt(6)" ::: "memory");
  __builtin_amdgcn_s_barrier();

  const int NT = Kd >> 6;
  bf16x8 af[4][2], bfr[4][2];

#define BAR()                                            \
  do {                                                   \
    asm volatile("" ::: "memory");                       \
    __builtin_amdgcn_s_barrier();                        \
    asm volatile("" ::: "memory");                       \
  } while (0)

#define MFMA_QUAD(MB, NB)                                                          \
  do {                                                                             \
    _Pragma("unroll") for (int m = 0; m < 4; ++m)                                  \
      _Pragma("unroll") for (int n = 0; n < 2; ++n) {                              \
        acc[(MB) + m][(NB) + n] = __builtin_amdgcn_mfma_f32_16x16x32_bf16(         \
            af[m][0], bfr[(NB) + n][0], acc[(MB) + m][(NB) + n], 0, 0, 0);         \
        acc[(MB) + m][(NB) + n] = __builtin_amdgcn_mfma_f32_16x16x32_bf16(         \
            af[m][1], bfr[(NB) + n][1], acc[(MB) + m][(NB) + n], 0, 0, 0);         \
      }                                                                            \
  } while (0)

#define TILE_BODY(T, BUF)                                                       \
  do {                                                                          \
    const char* Ab = lds[BUF][2 + wr];                                          \
    const char* Bb = lds[BUF][wc >> 1];                                         \
    _Pragma("unroll") for (int m = 0; m < 4; ++m) {                             \
      af[m][0] = *(const bf16x8*)(Ab + arow + m * 2048 + c0);                   \
      af[m][1] = *(const bf16x8*)(Ab + arow + m * 2048 + c1);                   \
    }                                                                           \
    _Pragma("unroll") for (int n = 0; n < 4; ++n) {                             \
      bfr[n][0] = *(const bf16x8*)(Bb + brow + n * 2048 + c0);                  \
      bfr[n][1] = *(const bf16x8*)(Bb + brow + n * 2048 + c1);                  \
    }                                                                           \
    if ((T) + 1 < NT) stageHT((T) + 1, 3, (BUF) ^ 1);                           \
    BAR();                                                                      \
    __builtin_amdgcn_s_setprio(1);                                              \
    MFMA_QUAD(0, 0);                                                            \
    __builtin_amdgcn_s_setprio(0);                                              \
    asm volatile("s_waitcnt lgkmcnt(0)" ::: "memory");                          \
    BAR();                                                                      \
    if ((T) + 2 < NT) stageHT((T) + 2, 0, BUF);                                 \
    BAR();                                                                      \
    __builtin_amdgcn_s_setprio(1);                                              \
    MFMA_QUAD(0, 2);                                                            \
    __builtin_amdgcn_s_setprio(0);                                              \
    BAR();                                                                      \
    _Pragma("unroll") for (int m = 0; m < 4; ++m) {                             \
      af[m][0] = *(const bf16x8*)(Ab + arow + (m + 4) * 2048 + c0);             \
      af[m][1] = *(const bf16x8*)(Ab + arow + (m + 4) * 2048 + c1);             \
    }                                                                           \
    if ((T) + 2 < NT) stageHT((T) + 2, 1, BUF);                                 \
    BAR();                                                                      \
    __builtin_amdgcn_s_setprio(1);                                              \
    MFMA_QUAD(4, 0);                                                            \
    __builtin_amdgcn_s_setprio(0);                                              \
    asm volatile("s_waitcnt lgkmcnt(0)" ::: "memory");                          \
    BAR();                                                                      \
    if ((T) + 2 < NT) stageHT((T) + 2, 2, BUF);                                 \
    BAR();                                                                      \
    __builtin_amdgcn_s_setprio(1);                                              \
    MFMA_QUAD(4, 2);                                                            \
    __builtin_amdgcn_s_setprio(0);                                              \
    if ((T) + 2 < NT) { asm volatile("s_waitcnt vmcnt(6)" ::: "memory"); }      \
    else { asm volatile("s_waitcnt vmcnt(0)" ::: "memory"); }                   \
    BAR();                                                                      \
  } while (0)

  for (int tp = 0; tp < NT; tp += 2) {
    TILE_BODY(tp, 0);
    TILE_BODY(tp + 1, 1);
  }
#undef TILE_BODY
#undef MFMA_QUAD
#undef BAR

  const int seg = N0 >> 11;               // 0:Q 1:K
  const int nbase = N0 & 2047;
  const float* bb = (seg == 0) ? bq : bk;
  __bf16* dst = (seg == 0) ? Qout : Kout;
#pragma unroll
  for (int m = 0; m < 8; ++m) {
#pragma unroll
    for (int n = 0; n < 4; ++n) {
      const int col = nbase + wc * 64 + n * 16 + lm;
      const float bvv = bb[col];
#pragma unroll
      for (int i = 0; i < 4; ++i) {
        const int row = M0 + wr * 128 + m * 16 + lq * 4 + i;
        dst[(size_t)row * 2048 + col] = (__bf16)(acc[m][n][i] + bvv);
      }
    }
  }
}

// ---------- MFMA flash attention v7: v5 + slot XOR-swizzle (T2) -------------
// LDS chunks are 64 slots x 16B; physical slot = s ^ ((s>>3)&7) (involution).
// Old linear slots put 8 lanes on the same 4-bank group (slot*16 stride-128
// aliasing) -> 8-way conflict on every kf/vf ds_read_b128 (1.05e7 conflicts).
// Swizzle applied BOTH sides: reads (sl16), K staging global source (slog),
// V ds_write placement (o_a / o_a^16). 2 lanes/bank-group per quarter = free.
__global__ __launch_bounds__(256, 2) void attn_mfma(
    const __bf16* __restrict__ Q, const __bf16* __restrict__ K,
    const __bf16* __restrict__ Vt, __bf16* __restrict__ O) {
  __shared__ __attribute__((aligned(16))) char KsL[2][16 * 1024];
  __shared__ __attribute__((aligned(16))) char VsL[2][16 * 1024];

  const int t = threadIdx.x;
  const int w = t >> 6, l = t & 63;
  const int lm = l & 15, quad = l >> 4;
  const int flat = (blockIdx.z * gridDim.y + blockIdx.y) * gridDim.x + blockIdx.x;
  const int swz = (flat & 7) * 64 + (flat >> 3);
  const int b = swz >> 8;
  const int h = (swz >> 4) & 15;
  const int q0 = (swz & 15) * 128;
  const size_t Ds = 2048;
  const size_t hoff = (size_t)h * 128;
  const size_t bbase = (size_t)b * 2048;
  const int slq = (lm << 2) | quad;
  const int sl16 = (slq ^ ((slq >> 3) & 7)) * 16;   // swizzled read offset
  const float SCL = 0.08838834764831845f * 1.4426950408889634f;

  // K staging: global_load_lds writes lane l -> phys slot l; lane l must load
  // the global data of LOGICAL slot slog = l ^ ((l>>3)&7) (involution).
  const int slog = l ^ ((l >> 3) & 7);
  const int krow = slog >> 2, kcol = (slog & 3) * 8;
  const int vth = l & 3, vd = l >> 2;

  bf16x8 qf[2][4];
#pragma unroll
  for (int ntq = 0; ntq < 2; ++ntq)
#pragma unroll
    for (int ks = 0; ks < 4; ++ks)
      qf[ntq][ks] = *(const bf16x8*)(Q + (bbase + q0 + w * 32 + ntq * 16 + lm) * Ds + hoff + ks * 32 + quad * 8);

  f32x4 oacc[2][8];
#pragma unroll
  for (int ntq = 0; ntq < 2; ++ntq)
#pragma unroll
    for (int nv = 0; nv < 8; ++nv)
#pragma unroll
      for (int e = 0; e < 4; ++e) oacc[ntq][nv][e] = 0.f;
  float lpart[2] = {0.f, 0.f};

  bf16x8 vreg[4];

  auto loadV = [&](int kt) {
#pragma unroll
    for (int i = 0; i < 4; ++i) {
      const int chunk = w * 4 + i;
      const int nv = chunk >> 1, c = chunk & 1;
      vreg[i] = *(const bf16x8*)(Vt + (bbase + hoff + nv * 16 + vd) * Ds + kt + c * 32 + vth * 8);
    }
  };
  auto stageK = [&](int kt, char* Kb) {
#pragma unroll
    for (int i = 0; i < 4; ++i) {
      const __bf16* src = K + (bbase + kt + i * 16 + krow) * Ds + hoff + w * 32 + kcol;
      __builtin_amdgcn_global_load_lds(GLB_AS(src), LDS_AS(Kb + (i * 4 + w) * 1024), 16, 0, 0);
    }
  };
  auto writeV = [&](char* Vb) {
    // logical slot_a (even); phys = slot_a ^ (slot_a>>3) = slot_a ^ (vd>>1).
    // second half-pair goes to phys(slot_a+1) = phys_a ^ 1 -> offset ^16.
    const int slot_a = (vd << 2) | ((vth & 1) << 1);
    const int o_a = (slot_a ^ ((vd >> 1) & 7)) * 16 + (vth >> 1) * 8;
#pragma unroll
    for (int i = 0; i < 4; ++i) {
      char* base = Vb + (w * 4 + i) * 1024;
      uint4 u = *(const uint4*)&vreg[i];
      *(uint2*)(base + o_a) = make_uint2(u.x, u.y);
      *(uint2*)(base + (o_a ^ 16)) = make_uint2(u.z, u.w);
    }
  };

  loadV(0);
  stageK(0, KsL[0]);
  writeV(VsL[0]);

  for (int it = 0; it < 32; ++it) {
    __syncthreads();
    const int cur = it & 1;
    const bool more = (it + 1) < 32;
    if (more) { loadV((it + 1) * 64); stageK((it + 1) * 64, KsL[(it + 1) & 1]); }

    const char* Kb = KsL[cur];
    const char* Vb = VsL[cur];

    f32x4 st[4][2];
#pragma unroll
    for (int mtk = 0; mtk < 4; ++mtk)
#pragma unroll
      for (int ntq = 0; ntq < 2; ++ntq)
#pragma unroll
        for (int e = 0; e < 4; ++e) st[mtk][ntq][e] = 0.f;
    __builtin_amdgcn_s_setprio(1);
#pragma unroll
    for (int ks = 0; ks < 4; ++ks) {
#pragma unroll
      for (int mtk = 0; mtk < 4; ++mtk) {
        bf16x8 kf = *(const bf16x8*)(Kb + (mtk * 4 + ks) * 1024 + sl16);
        st[mtk][0] = __builtin_amdgcn_mfma_f32_16x16x32_bf16(kf, qf[0][ks], st[mtk][0], 0, 0, 0);
        st[mtk][1] = __builtin_amdgcn_mfma_f32_16x16x32_bf16(kf, qf[1][ks], st[mtk][1], 0, 0, 0);
      }
    }
    __builtin_amdgcn_s_setprio(0);

#pragma unroll
    for (int c = 0; c < 2; ++c) {
      bf16x8 pf[2];
#pragma unroll
      for (int ntq = 0; ntq < 2; ++ntq) {
#pragma unroll
        for (int half = 0; half < 2; ++half) {
          const f32x4 sv = st[c * 2 + half][ntq];
#pragma unroll
          for (int r = 0; r < 4; ++r) {
            const float p = exp2f(sv[r] * SCL);
            const __bf16 pb = (__bf16)p;
            pf[ntq][half * 4 + r] = pb;
            lpart[ntq] += (float)pb;
          }
        }
      }
      __builtin_amdgcn_s_setprio(1);
#pragma unroll
      for (int nv = 0; nv < 8; ++nv) {
        bf16x8 vf = *(const bf16x8*)(Vb + (nv * 2 + c) * 1024 + sl16);
        oacc[0][nv] = __builtin_amdgcn_mfma_f32_16x16x32_bf16(pf[0], vf, oacc[0][nv], 0, 0, 0);
        oacc[1][nv] = __builtin_amdgcn_mfma_f32_16x16x32_bf16(pf[1], vf, oacc[1][nv], 0, 0, 0);
      }
      __builtin_amdgcn_s_setprio(0);
    }

    if (more) writeV(VsL[(it + 1) & 1]);
  }

  float linv[2];
#pragma unroll
  for (int ntq = 0; ntq < 2; ++ntq) {
    float v = lpart[ntq];
    v += __shfl_xor(v, 16, 64);
    v += __shfl_xor(v, 32, 64);
    linv[ntq] = 1.f / v;
  }
  float oinv[2][4];
#pragma unroll
  for (int ntq = 0; ntq < 2; ++ntq)
#pragma unroll
    for (int r = 0; r < 4; ++r)
      oinv[ntq][r] = __shfl(linv[ntq], quad * 4 + r, 64);

#pragma unroll
  for (int ntq = 0; ntq < 2; ++ntq)
#pragma unroll
    for (int nv = 0; nv < 8; ++nv)
#pragma unroll
      for (int r = 0; r < 4; ++r) {
        const int qrow = q0 + w * 32 + ntq * 16 + quad * 4 + r;
        O[(bbase + qrow) * Ds + hoff + nv * 16 + lm] = (__bf16)(oacc[ntq][nv][r] * oinv[ntq][r]);
      }
}

// ---------- launch ----------
extern "C" void kernel_launch(void* const* d_in, const int* in_sizes, int n_in,
                              void* d_out, int out_size, void* d_ws, size_t ws_size,
                              hipStream_t stream) {
  const float* x      = (const float*)d_in[0];
  const float* Wq     = (const float*)d_in[1];
  const float* bq     = (const float*)d_in[2];
  const float* Wk     = (const float*)d_in[3];
  const float* bk     = (const float*)d_in[4];
  const float* Wv     = (const float*)d_in[5];
  const float* bv     = (const float*)d_in[6];
  const float* Wo     = (const float*)d_in[7];
  const float* bo     = (const float*)d_in[8];
  const float* scale1 = (const float*)d_in[9];
  const float* scale2 = (const float*)d_in[10];
  const float* W1     = (const float*)d_in[11];
  const float* W2     = (const float*)d_in[12];
  const float* W3     = (const float*)d_in[13];

  const int M = 4096, N = 2048, Kd = 2048;
  char* ws = (char*)d_ws;
  const size_t WT_B = (size_t)2048 * 2048 * 2;   // 8 MB
  const size_t ACT_B = (size_t)4096 * 2048 * 2;  // 16 MB
  __bf16* wt[7];
  size_t off = 0;
  for (int i = 0; i < 7; ++i) { wt[i] = (__bf16*)(ws + off); off += WT_B; }
  __bf16* hn1  = (__bf16*)(ws + off); off += ACT_B;
  __bf16* Qb   = (__bf16*)(ws + off); off += ACT_B;
  __bf16* Kb   = (__bf16*)(ws + off); off += ACT_B;
  __bf16* VtG  = (__bf16*)(ws + off); off += ACT_B;
  __bf16* attn = (__bf16*)(ws + off); off += ACT_B;
  __bf16* hn2  = (__bf16*)(ws + off); off += ACT_B;
  __bf16* x1b  = (__bf16*)(ws + off); off += ACT_B;
  __bf16* fmb  = (__bf16*)(ws + off); off += ACT_B;

  dim3 tb(256);
  {
    TP p;
    p.s[0] = Wq; p.s[1] = Wk; p.s[2] = Wv; p.s[3] = Wo; p.s[4] = W1; p.s[5] = W2; p.s[6] = W3;
    for (int i = 0; i < 7; ++i) p.d[i] = wt[i];
    transpose_convert_all<<<dim3(64, 64, 7), tb, 0, stream>>>(p);
  }

  rmsnorm_k<<<4096, tb, 0, stream>>>(x, scale1, hn1);

  // QK GEMM: 256^2 8-phase over N 0..4095, 256 blocks = 1 perfect round
  gemm_qkv<<<dim3(16, 16), dim3(512), 0, stream>>>(hn1, wt[0], bq, bk, Qb, Kb, Kd);
  // V GEMM: 128^2 structure, transposed epilogue, 512 blocks = 2 perfect rounds
  gemm_bt<false, true, false, false, true><<<dim3(16, 32), tb, 0, stream>>>(
      hn1, wt[2], bv, nullptr, nullptr, VtG, M, 2048, Kd);

  dim3 ag(2048 / 128, 16, 2);
  attn_mfma<<<ag, tb, 0, stream>>>(Qb, Kb, VtG, attn);

  dim3 gg(N / 128, M / 128);
  gemm_bt<true, true, true, false><<<gg, tb, 0, stream>>>(attn, wt[3], bo, x, nullptr, d_out, M, N, Kd);

  rmsnorm_k<<<4096, tb, 0, stream>>>((const float*)d_out, scale2, hn2);

  gemm_bt<false, false, false, false><<<gg, tb, 0, stream>>>(hn2, wt[4], nullptr, nullptr, nullptr, x1b, M, N, Kd);
  gemm_bt<false, false, false, true><<<gg, tb, 0, stream>>>(x1b, wt[5], nullptr, nullptr, x1b, fmb, M, N, Kd);
  gemm_bt<true, false, true, false><<<gg, tb, 0, stream>>>(fmb, wt[6], nullptr, x, nullptr, d_out, M, N, Kd);
}

// Round 8
// 603.022 us; speedup vs baseline: 1.0511x; 1.0151x over previous
//
#include <hip/hip_runtime.h>

// ---------- types ----------
typedef __bf16 bf16x8 __attribute__((ext_vector_type(8)));
typedef __bf16 bf16x4v __attribute__((ext_vector_type(4)));
typedef float  f32x4  __attribute__((ext_vector_type(4)));

#define LDS_AS(p) ((__attribute__((address_space(3))) void*)(p))
#define GLB_AS(p) ((const __attribute__((address_space(1))) void*)(p))

// 1/sqrt(128) * log2(e): folded into Wq/bq so attn exp2f needs no multiply.
#define QSCL (0.08838834764831845f * 1.4426950408889634f)

// ---------- batched weight f32 -> bf16 transposed: Wt[n][k] = W[k][n]*sc ------
struct TP { const float* s[7]; __bf16* d[7]; float sc[7]; };
__global__ __launch_bounds__(256) void transpose_convert_all(TP p) {
  const float* __restrict__ W = p.s[blockIdx.z];
  __bf16* __restrict__ Wt = p.d[blockIdx.z];
  const float sc = p.sc[blockIdx.z];
  __shared__ float tile[32][33];
  const int tx = threadIdx.x & 31, ty = threadIdx.x >> 5;
  const int n0 = blockIdx.x * 32, k0 = blockIdx.y * 32;
#pragma unroll
  for (int j = 0; j < 4; ++j)
    tile[ty + j * 8][tx] = W[(size_t)(k0 + ty + j * 8) * 2048 + n0 + tx];
  __syncthreads();
#pragma unroll
  for (int j = 0; j < 4; ++j)
    Wt[(size_t)(n0 + ty + j * 8) * 2048 + k0 + tx] = (__bf16)(tile[tx][ty + j * 8] * sc);
}

// ---------- RMSNorm: f32 in -> bf16 out, D=2048, one block per row ----------
__global__ __launch_bounds__(256) void rmsnorm_k(
    const float* __restrict__ x, const float* __restrict__ scale,
    __bf16* __restrict__ out) {
  const int row = blockIdx.x, t = threadIdx.x;
  const float4* xr = (const float4*)(x + (size_t)row * 2048);
  float4 a = xr[t], b2 = xr[t + 256];
  float ss = a.x * a.x + a.y * a.y + a.z * a.z + a.w * a.w +
             b2.x * b2.x + b2.y * b2.y + b2.z * b2.z + b2.w * b2.w;
#pragma unroll
  for (int ofs = 32; ofs; ofs >>= 1) ss += __shfl_xor(ss, ofs, 64);
  __shared__ float red[4];
  if ((t & 63) == 0) red[t >> 6] = ss;
  __syncthreads();
  ss = red[0] + red[1] + red[2] + red[3];
  const float rs = rsqrtf(ss * (1.f / 2048.f) + 1e-5f);
  const float4* sr = (const float4*)scale;
  float4 s1 = sr[t], s2 = sr[t + 256];
  __bf16* orow = out + (size_t)row * 2048;
  orow[t * 4 + 0] = (__bf16)(a.x * rs * s1.x);
  orow[t * 4 + 1] = (__bf16)(a.y * rs * s1.y);
  orow[t * 4 + 2] = (__bf16)(a.z * rs * s1.z);
  orow[t * 4 + 3] = (__bf16)(a.w * rs * s1.w);
  orow[(t + 256) * 4 + 0] = (__bf16)(b2.x * rs * s2.x);
  orow[(t + 256) * 4 + 1] = (__bf16)(b2.y * rs * s2.y);
  orow[(t + 256) * 4 + 2] = (__bf16)(b2.z * rs * s2.z);
  orow[(t + 256) * 4 + 3] = (__bf16)(b2.w * rs * s2.w);
}

// ---------- GEMM: C[M,N] = A[M,K] @ Bt[N,K]^T, dbuf single-barrier (128^2) ----
// + T1 XCD-chunked swizzle (512 blocks at all call sites, 512%8==0).
// VTRANS: write C transposed as Vt[(b*2048+col)][token] bf16x4-packed (+bias).
template <bool OUTF32, bool HASBIAS, bool HASRES, bool SILU, bool VTRANS = false>
__global__ __launch_bounds__(256) void gemm_bt(
    const __bf16* __restrict__ A, const __bf16* __restrict__ Bt,
    const float* __restrict__ bias, const float* __restrict__ res,
    const __bf16* __restrict__ ew, void* __restrict__ Cout,
    int M, int N, int Kd) {
  __shared__ __attribute__((aligned(16))) __bf16 As[2][128 * 32];
  __shared__ __attribute__((aligned(16))) __bf16 Bs[2][128 * 32];
  const int tid = threadIdx.x;
  const int w = tid >> 6, l = tid & 63;
  const int flat = blockIdx.y * gridDim.x + blockIdx.x;
  const int nwg = gridDim.x * gridDim.y;          // 512 at all call sites
  const int swz = (flat & 7) * (nwg >> 3) + (flat >> 3);
  const int bx = swz % gridDim.x, by = swz / gridDim.x;
  const int M0 = by * 128, N0 = bx * 128;
  const int wr = w >> 1, wc = w & 1;
  const int lm = l & 15, lq = l >> 4;

  f32x4 acc[4][4];
#pragma unroll
  for (int mt = 0; mt < 4; ++mt)
#pragma unroll
    for (int nt = 0; nt < 4; ++nt)
#pragma unroll
      for (int e = 0; e < 4; ++e) acc[mt][nt][e] = 0.f;

  const int offA0 = (w * 2 + 0) * 1024 + l * 16;
  const int offA1 = (w * 2 + 1) * 1024 + l * 16;
  const int row0 = offA0 >> 6, kb0 = offA0 & 63;
  const int row1 = offA1 >> 6, kb1 = offA1 & 63;
  const int nIt = Kd >> 5;

  auto stage = [&](int k0, int bsel) {
    const char* ga0 = (const char*)(A + (size_t)(M0 + row0) * Kd + k0) + kb0;
    const char* ga1 = (const char*)(A + (size_t)(M0 + row1) * Kd + k0) + kb1;
    const char* gb0 = (const char*)(Bt + (size_t)(N0 + row0) * Kd + k0) + kb0;
    const char* gb1 = (const char*)(Bt + (size_t)(N0 + row1) * Kd + k0) + kb1;
    __builtin_amdgcn_global_load_lds(GLB_AS(ga0), LDS_AS(((char*)As[bsel]) + (w * 2 + 0) * 1024), 16, 0, 0);
    __builtin_amdgcn_global_load_lds(GLB_AS(ga1), LDS_AS(((char*)As[bsel]) + (w * 2 + 1) * 1024), 16, 0, 0);
    __builtin_amdgcn_global_load_lds(GLB_AS(gb0), LDS_AS(((char*)Bs[bsel]) + (w * 2 + 0) * 1024), 16, 0, 0);
    __builtin_amdgcn_global_load_lds(GLB_AS(gb1), LDS_AS(((char*)Bs[bsel]) + (w * 2 + 1) * 1024), 16, 0, 0);
  };

  stage(0, 0);
  for (int it = 0; it < nIt; ++it) {
    __syncthreads();
    if (it + 1 < nIt) stage((it + 1) * 32, (it + 1) & 1);
    const __bf16* Ab = As[it & 1];
    const __bf16* Bb = Bs[it & 1];
    bf16x8 af[4], bfr[4];
#pragma unroll
    for (int mt = 0; mt < 4; ++mt)
      af[mt] = *(const bf16x8*)(Ab + (wr * 64 + mt * 16 + lm) * 32 + lq * 8);
#pragma unroll
    for (int nt = 0; nt < 4; ++nt)
      bfr[nt] = *(const bf16x8*)(Bb + (wc * 64 + nt * 16 + lm) * 32 + lq * 8);
#pragma unroll
    for (int mt = 0; mt < 4; ++mt)
#pragma unroll
      for (int nt = 0; nt < 4; ++nt)
        acc[mt][nt] = __builtin_amdgcn_mfma_f32_16x16x32_bf16(af[mt], bfr[nt], acc[mt][nt], 0, 0, 0);
  }

  const int lr = lq * 4;
#pragma unroll
  for (int mt = 0; mt < 4; ++mt) {
#pragma unroll
    for (int nt = 0; nt < 4; ++nt) {
      const int col = N0 + wc * 64 + nt * 16 + lm;
      float bv = 0.f;
      if (HASBIAS) bv = bias[col];
      if (VTRANS) {
        const int rw0 = M0 + wr * 64 + mt * 16 + lr;
        const int bidx = rw0 >> 11, tok = rw0 & 2047;
        bf16x4v pk;
#pragma unroll
        for (int i = 0; i < 4; ++i) pk[i] = (__bf16)(acc[mt][nt][i] + bv);
        *(bf16x4v*)((__bf16*)Cout + ((size_t)(bidx * 2048 + col)) * 2048 + tok) = pk;
      } else {
#pragma unroll
        for (int i = 0; i < 4; ++i) {
          const int row = M0 + wr * 64 + mt * 16 + lr + i;
          const size_t off = (size_t)row * N + col;
          float v = acc[mt][nt][i] + bv;
          if (HASRES) v += res[off];
          if (SILU) {
            const float x1v = (float)ew[off];
            v = x1v * (1.f / (1.f + __expf(-x1v))) * v;
          }
          if (OUTF32) ((float*)Cout)[off] = v;
          else ((__bf16*)Cout)[off] = (__bf16)v;
        }
      }
    }
  }
}

// ---------- fused QK GEMM: 256^2 tile, BK=64, 8 waves, 8-phase counted-vmcnt ----
// Covers ONLY Q,K (N 0..4095): grid 16x16 = 256 blocks = one perfect round.
// Wq/bq are pre-scaled by QSCL (attn softmax scale folded into Q).
__global__ __launch_bounds__(512, 2) void gemm_qkv(
    const __bf16* __restrict__ A, const __bf16* __restrict__ Bt,
    const float* __restrict__ bq, const float* __restrict__ bk,
    __bf16* __restrict__ Qout, __bf16* __restrict__ Kout, int Kd) {
  __shared__ __attribute__((aligned(16))) char lds[2][4][16384];

  const int tid = threadIdx.x;
  const int w = tid >> 6, l = tid & 63;
  const int wr = w >> 2, wc = w & 3;
  const int lm = l & 15, lq = l >> 4;

  const int flat = blockIdx.y * 16 + blockIdx.x;
  const int swz = (flat & 7) * 32 + (flat >> 3);
  const int bx = swz >> 4, by = swz & 15;
  const int N0 = bx * 256, M0 = by * 256;

  const int srow = w * 8 + (l >> 3);
  const int scol = ((l & 7) ^ (l >> 3)) * 8;
  const __bf16* aS = A + (size_t)(M0 + srow) * Kd + scol;
  const __bf16* bS = Bt + (size_t)(N0 + srow) * Kd + scol;

  auto stageHT = [&](int t, int s, int db) {
    char* dst = lds[db][s] + w * 1024;
    const __bf16* src = (s >= 2) ? (aS + (size_t)(s - 2) * 128 * Kd + t * 64)
                                 : (bS + (size_t)s * 128 * Kd + t * 64);
    __builtin_amdgcn_global_load_lds(GLB_AS(src), LDS_AS(dst), 16, 0, 0);
    __builtin_amdgcn_global_load_lds(GLB_AS(src + (size_t)64 * Kd), LDS_AS(dst + 8192), 16, 0, 0);
  };

  f32x4 acc[8][4];
#pragma unroll
  for (int m = 0; m < 8; ++m)
#pragma unroll
    for (int n = 0; n < 4; ++n)
#pragma unroll
      for (int e = 0; e < 4; ++e) acc[m][n][e] = 0.f;

  const int swzr = (lm & 7) << 4;
  const int c0 = (lq * 16) ^ swzr;
  const int c1 = ((64 + lq * 16)) ^ swzr;
  const int arow = lm * 128;
  const int brow = ((wc & 1) * 64 + lm) * 128;

  stageHT(0, 0, 0); stageHT(0, 1, 0); stageHT(0, 2, 0); stageHT(0, 3, 0);
  stageHT(1, 0, 1); stageHT(1, 1, 1); stageHT(1, 2, 1);
  asm volatile("s_waitcnt vmcnt(6)" ::: "memory");
  __builtin_amdgcn_s_barrier();

  const int NT = Kd >> 6;
  bf16x8 af[4][2], bfr[4][2];

#define BAR()                                            \
  do {                                                   \
    asm volatile("" ::: "memory");                       \
    __builtin_amdgcn_s_barrier();                        \
    asm volatile("" ::: "memory");                       \
  } while (0)

#define MFMA_QUAD(MB, NB)                                                          \
  do {                                                                             \
    _Pragma("unroll") for (int m = 0; m < 4; ++m)                                  \
      _Pragma("unroll") for (int n = 0; n < 2; ++n) {                              \
        acc[(MB) + m][(NB) + n] = __builtin_amdgcn_mfma_f32_16x16x32_bf16(         \
            af[m][0], bfr[(NB) + n][0], acc[(MB) + m][(NB) + n], 0, 0, 0);         \
        acc[(MB) + m][(NB) + n] = __builtin_amdgcn_mfma_f32_16x16x32_bf16(         \
            af[m][1], bfr[(NB) + n][1], acc[(MB) + m][(NB) + n], 0, 0, 0);         \
      }                                                                            \
  } while (0)

#define TILE_BODY(T, BUF)                                                       \
  do {                                                                          \
    const char* Ab = lds[BUF][2 + wr];                                          \
    const char* Bb = lds[BUF][wc >> 1];                                         \
    _Pragma("unroll") for (int m = 0; m < 4; ++m) {                             \
      af[m][0] = *(const bf16x8*)(Ab + arow + m * 2048 + c0);                   \
      af[m][1] = *(const bf16x8*)(Ab + arow + m * 2048 + c1);                   \
    }                                                                           \
    _Pragma("unroll") for (int n = 0; n < 4; ++n) {                             \
      bfr[n][0] = *(const bf16x8*)(Bb + brow + n * 2048 + c0);                  \
      bfr[n][1] = *(const bf16x8*)(Bb + brow + n * 2048 + c1);                  \
    }                                                                           \
    if ((T) + 1 < NT) stageHT((T) + 1, 3, (BUF) ^ 1);                           \
    BAR();                                                                      \
    __builtin_amdgcn_s_setprio(1);                                              \
    MFMA_QUAD(0, 0);                                                            \
    __builtin_amdgcn_s_setprio(0);                                              \
    asm volatile("s_waitcnt lgkmcnt(0)" ::: "memory");                          \
    BAR();                                                                      \
    if ((T) + 2 < NT) stageHT((T) + 2, 0, BUF);                                 \
    BAR();                                                                      \
    __builtin_amdgcn_s_setprio(1);                                              \
    MFMA_QUAD(0, 2);                                                            \
    __builtin_amdgcn_s_setprio(0);                                              \
    BAR();                                                                      \
    _Pragma("unroll") for (int m = 0; m < 4; ++m) {                             \
      af[m][0] = *(const bf16x8*)(Ab + arow + (m + 4) * 2048 + c0);             \
      af[m][1] = *(const bf16x8*)(Ab + arow + (m + 4) * 2048 + c1);             \
    }                                                                           \
    if ((T) + 2 < NT) stageHT((T) + 2, 1, BUF);                                 \
    BAR();                                                                      \
    __builtin_amdgcn_s_setprio(1);                                              \
    MFMA_QUAD(4, 0);                                                            \
    __builtin_amdgcn_s_setprio(0);                                              \
    asm volatile("s_waitcnt lgkmcnt(0)" ::: "memory");                          \
    BAR();                                                                      \
    if ((T) + 2 < NT) stageHT((T) + 2, 2, BUF);                                 \
    BAR();                                                                      \
    __builtin_amdgcn_s_setprio(1);                                              \
    MFMA_QUAD(4, 2);                                                            \
    __builtin_amdgcn_s_setprio(0);                                              \
    if ((T) + 2 < NT) { asm volatile("s_waitcnt vmcnt(6)" ::: "memory"); }      \
    else { asm volatile("s_waitcnt vmcnt(0)" ::: "memory"); }                   \
    BAR();                                                                      \
  } while (0)

  for (int tp = 0; tp < NT; tp += 2) {
    TILE_BODY(tp, 0);
    TILE_BODY(tp + 1, 1);
  }
#undef TILE_BODY
#undef MFMA_QUAD
#undef BAR

  const int seg = N0 >> 11;               // 0:Q 1:K
  const int nbase = N0 & 2047;
  const float* bb = (seg == 0) ? bq : bk;
  const float bsc = (seg == 0) ? QSCL : 1.f;   // bq pre-scaled like Wq
  __bf16* dst = (seg == 0) ? Qout : Kout;
#pragma unroll
  for (int m = 0; m < 8; ++m) {
#pragma unroll
    for (int n = 0; n < 4; ++n) {
      const int col = nbase + wc * 64 + n * 16 + lm;
      const float bvv = bb[col] * bsc;
#pragma unroll
      for (int i = 0; i < 4; ++i) {
        const int row = M0 + wr * 128 + m * 16 + lq * 4 + i;
        dst[(size_t)row * 2048 + col] = (__bf16)(acc[m][n][i] + bvv);
      }
    }
  }
}

// ---------- MFMA flash attention v8: v7 + ones-MFMA rowsum + pre-scaled Q ----
// Softmax VALU cut: (a) Q carries QSCL -> p = exp2f(sv) (no mul);
// (b) row-sum of P computed by mfma(pf, ones, lacc) on the matrix pipe --
// exactly equal to summing bf16-rounded P in f32, and it lands in C-layout
// row q=quad*4+r so the epilogue needs no cross-lane shuffles.
__global__ __launch_bounds__(256, 2) void attn_mfma(
    const __bf16* __restrict__ Q, const __bf16* __restrict__ K,
    const __bf16* __restrict__ Vt, __bf16* __restrict__ O) {
  __shared__ __attribute__((aligned(16))) char KsL[2][16 * 1024];
  __shared__ __attribute__((aligned(16))) char VsL[2][16 * 1024];

  const int t = threadIdx.x;
  const int w = t >> 6, l = t & 63;
  const int lm = l & 15, quad = l >> 4;
  const int flat = (blockIdx.z * gridDim.y + blockIdx.y) * gridDim.x + blockIdx.x;
  const int swz = (flat & 7) * 64 + (flat >> 3);
  const int b = swz >> 8;
  const int h = (swz >> 4) & 15;
  const int q0 = (swz & 15) * 128;
  const size_t Ds = 2048;
  const size_t hoff = (size_t)h * 128;
  const size_t bbase = (size_t)b * 2048;
  const int slq = (lm << 2) | quad;
  const int sl16 = (slq ^ ((slq >> 3) & 7)) * 16;   // swizzled read offset

  const int slog = l ^ ((l >> 3) & 7);
  const int krow = slog >> 2, kcol = (slog & 3) * 8;
  const int vth = l & 3, vd = l >> 2;

  bf16x8 onesv;
#pragma unroll
  for (int i = 0; i < 8; ++i) onesv[i] = (__bf16)1.0f;

  bf16x8 qf[2][4];
#pragma unroll
  for (int ntq = 0; ntq < 2; ++ntq)
#pragma unroll
    for (int ks = 0; ks < 4; ++ks)
      qf[ntq][ks] = *(const bf16x8*)(Q + (bbase + q0 + w * 32 + ntq * 16 + lm) * Ds + hoff + ks * 32 + quad * 8);

  f32x4 oacc[2][8];
#pragma unroll
  for (int ntq = 0; ntq < 2; ++ntq)
#pragma unroll
    for (int nv = 0; nv < 8; ++nv)
#pragma unroll
      for (int e = 0; e < 4; ++e) oacc[ntq][nv][e] = 0.f;
  f32x4 lacc[2];
#pragma unroll
  for (int ntq = 0; ntq < 2; ++ntq)
#pragma unroll
    for (int e = 0; e < 4; ++e) lacc[ntq][e] = 0.f;

  bf16x8 vreg[4];

  auto loadV = [&](int kt) {
#pragma unroll
    for (int i = 0; i < 4; ++i) {
      const int chunk = w * 4 + i;
      const int nv = chunk >> 1, c = chunk & 1;
      vreg[i] = *(const bf16x8*)(Vt + (bbase + hoff + nv * 16 + vd) * Ds + kt + c * 32 + vth * 8);
    }
  };
  auto stageK = [&](int kt, char* Kb) {
#pragma unroll
    for (int i = 0; i < 4; ++i) {
      const __bf16* src = K + (bbase + kt + i * 16 + krow) * Ds + hoff + w * 32 + kcol;
      __builtin_amdgcn_global_load_lds(GLB_AS(src), LDS_AS(Kb + (i * 4 + w) * 1024), 16, 0, 0);
    }
  };
  auto writeV = [&](char* Vb) {
    const int slot_a = (vd << 2) | ((vth & 1) << 1);
    const int o_a = (slot_a ^ ((vd >> 1) & 7)) * 16 + (vth >> 1) * 8;
#pragma unroll
    for (int i = 0; i < 4; ++i) {
      char* base = Vb + (w * 4 + i) * 1024;
      uint4 u = *(const uint4*)&vreg[i];
      *(uint2*)(base + o_a) = make_uint2(u.x, u.y);
      *(uint2*)(base + (o_a ^ 16)) = make_uint2(u.z, u.w);
    }
  };

  loadV(0);
  stageK(0, KsL[0]);
  writeV(VsL[0]);

  for (int it = 0; it < 32; ++it) {
    __syncthreads();
    const int cur = it & 1;
    const bool more = (it + 1) < 32;
    if (more) { loadV((it + 1) * 64); stageK((it + 1) * 64, KsL[(it + 1) & 1]); }

    const char* Kb = KsL[cur];
    const char* Vb = VsL[cur];

    f32x4 st[4][2];
#pragma unroll
    for (int mtk = 0; mtk < 4; ++mtk)
#pragma unroll
      for (int ntq = 0; ntq < 2; ++ntq)
#pragma unroll
        for (int e = 0; e < 4; ++e) st[mtk][ntq][e] = 0.f;
    __builtin_amdgcn_s_setprio(1);
#pragma unroll
    for (int ks = 0; ks < 4; ++ks) {
#pragma unroll
      for (int mtk = 0; mtk < 4; ++mtk) {
        bf16x8 kf = *(const bf16x8*)(Kb + (mtk * 4 + ks) * 1024 + sl16);
        st[mtk][0] = __builtin_amdgcn_mfma_f32_16x16x32_bf16(kf, qf[0][ks], st[mtk][0], 0, 0, 0);
        st[mtk][1] = __builtin_amdgcn_mfma_f32_16x16x32_bf16(kf, qf[1][ks], st[mtk][1], 0, 0, 0);
      }
    }
    __builtin_amdgcn_s_setprio(0);

#pragma unroll
    for (int c = 0; c < 2; ++c) {
      bf16x8 pf[2];
#pragma unroll
      for (int ntq = 0; ntq < 2; ++ntq) {
#pragma unroll
        for (int half = 0; half < 2; ++half) {
          const f32x4 sv = st[c * 2 + half][ntq];
#pragma unroll
          for (int r = 0; r < 4; ++r)
            pf[ntq][half * 4 + r] = (__bf16)exp2f(sv[r]);
        }
      }
      __builtin_amdgcn_s_setprio(1);
      lacc[0] = __builtin_amdgcn_mfma_f32_16x16x32_bf16(pf[0], onesv, lacc[0], 0, 0, 0);
      lacc[1] = __builtin_amdgcn_mfma_f32_16x16x32_bf16(pf[1], onesv, lacc[1], 0, 0, 0);
#pragma unroll
      for (int nv = 0; nv < 8; ++nv) {
        bf16x8 vf = *(const bf16x8*)(Vb + (nv * 2 + c) * 1024 + sl16);
        oacc[0][nv] = __builtin_amdgcn_mfma_f32_16x16x32_bf16(pf[0], vf, oacc[0][nv], 0, 0, 0);
        oacc[1][nv] = __builtin_amdgcn_mfma_f32_16x16x32_bf16(pf[1], vf, oacc[1][nv], 0, 0, 0);
      }
      __builtin_amdgcn_s_setprio(0);
    }

    if (more) writeV(VsL[(it + 1) & 1]);
  }

  // lacc[ntq][r] = total P-rowsum for qrow=quad*4+r (identical at every lm).
  float oinv[2][4];
#pragma unroll
  for (int ntq = 0; ntq < 2; ++ntq)
#pragma unroll
    for (int r = 0; r < 4; ++r)
      oinv[ntq][r] = 1.f / lacc[ntq][r];

#pragma unroll
  for (int ntq = 0; ntq < 2; ++ntq)
#pragma unroll
    for (int nv = 0; nv < 8; ++nv)
#pragma unroll
      for (int r = 0; r < 4; ++r) {
        const int qrow = q0 + w * 32 + ntq * 16 + quad * 4 + r;
        O[(bbase + qrow) * Ds + hoff + nv * 16 + lm] = (__bf16)(oacc[ntq][nv][r] * oinv[ntq][r]);
      }
}

// ---------- launch ----------
extern "C" void kernel_launch(void* const* d_in, const int* in_sizes, int n_in,
                              void* d_out, int out_size, void* d_ws, size_t ws_size,
                              hipStream_t stream) {
  const float* x      = (const float*)d_in[0];
  const float* Wq     = (const float*)d_in[1];
  const float* bq     = (const float*)d_in[2];
  const float* Wk     = (const float*)d_in[3];
  const float* bk     = (const float*)d_in[4];
  const float* Wv     = (const float*)d_in[5];
  const float* bv     = (const float*)d_in[6];
  const float* Wo     = (const float*)d_in[7];
  const float* bo     = (const float*)d_in[8];
  const float* scale1 = (const float*)d_in[9];
  const float* scale2 = (const float*)d_in[10];
  const float* W1     = (const float*)d_in[11];
  const float* W2     = (const float*)d_in[12];
  const float* W3     = (const float*)d_in[13];

  const int M = 4096, N = 2048, Kd = 2048;
  char* ws = (char*)d_ws;
  const size_t WT_B = (size_t)2048 * 2048 * 2;   // 8 MB
  const size_t ACT_B = (size_t)4096 * 2048 * 2;  // 16 MB
  __bf16* wt[7];
  size_t off = 0;
  for (int i = 0; i < 7; ++i) { wt[i] = (__bf16*)(ws + off); off += WT_B; }
  __bf16* hn1  = (__bf16*)(ws + off); off += ACT_B;
  __bf16* Qb   = (__bf16*)(ws + off); off += ACT_B;
  __bf16* Kb   = (__bf16*)(ws + off); off += ACT_B;
  __bf16* VtG  = (__bf16*)(ws + off); off += ACT_B;
  __bf16* attn = (__bf16*)(ws + off); off += ACT_B;
  __bf16* hn2  = (__bf16*)(ws + off); off += ACT_B;
  __bf16* x1b  = (__bf16*)(ws + off); off += ACT_B;
  __bf16* fmb  = (__bf16*)(ws + off); off += ACT_B;

  dim3 tb(256);
  {
    TP p;
    p.s[0] = Wq; p.s[1] = Wk; p.s[2] = Wv; p.s[3] = Wo; p.s[4] = W1; p.s[5] = W2; p.s[6] = W3;
    for (int i = 0; i < 7; ++i) { p.d[i] = wt[i]; p.sc[i] = 1.f; }
    p.sc[0] = QSCL;                       // fold softmax scale into Wq
    transpose_convert_all<<<dim3(64, 64, 7), tb, 0, stream>>>(p);
  }

  rmsnorm_k<<<4096, tb, 0, stream>>>(x, scale1, hn1);

  // QK GEMM: 256^2 8-phase over N 0..4095, 256 blocks = 1 perfect round
  gemm_qkv<<<dim3(16, 16), dim3(512), 0, stream>>>(hn1, wt[0], bq, bk, Qb, Kb, Kd);
  // V GEMM: 128^2 structure, transposed epilogue, 512 blocks = 2 perfect rounds
  gemm_bt<false, true, false, false, true><<<dim3(16, 32), tb, 0, stream>>>(
      hn1, wt[2], bv, nullptr, nullptr, VtG, M, 2048, Kd);

  dim3 ag(2048 / 128, 16, 2);
  attn_mfma<<<ag, tb, 0, stream>>>(Qb, Kb, VtG, attn);

  dim3 gg(N / 128, M / 128);
  gemm_bt<true, true, true, false><<<gg, tb, 0, stream>>>(attn, wt[3], bo, x, nullptr, d_out, M, N, Kd);

  rmsnorm_k<<<4096, tb, 0, stream>>>((const float*)d_out, scale2, hn2);

  gemm_bt<false, false, false, false><<<gg, tb, 0, stream>>>(hn2, wt[4], nullptr, nullptr, nullptr, x1b, M, N, Kd);
  gemm_bt<false, false, false, true><<<gg, tb, 0, stream>>>(x1b, wt[5], nullptr, nullptr, x1b, fmb, M, N, Kd);
  gemm_bt<true, false, true, false><<<gg, tb, 0, stream>>>(fmb, wt[6], nullptr, x, nullptr, d_out, M, N, Kd);
}

// Round 10
// 561.042 us; speedup vs baseline: 1.1297x; 1.0748x over previous
//
#include <hip/hip_runtime.h>

// ---------- types ----------
typedef __bf16 bf16x8 __attribute__((ext_vector_type(8)));
typedef __bf16 bf16x4v __attribute__((ext_vector_type(4)));
typedef float  f32x4  __attribute__((ext_vector_type(4)));

#define LDS_AS(p) ((__attribute__((address_space(3))) void*)(p))
#define GLB_AS(p) ((const __attribute__((address_space(1))) void*)(p))

// 1/sqrt(128) * log2(e): folded into Wq/bq so attn exp2f needs no multiply.
#define QSCL (0.08838834764831845f * 1.4426950408889634f)

// ---------- batched weight f32 -> bf16 transposed: Wt[n][k] = W[k][n]*sc ------
struct TP { const float* s[7]; __bf16* d[7]; float sc[7]; };
__global__ __launch_bounds__(256) void transpose_convert_all(TP p) {
  const float* __restrict__ W = p.s[blockIdx.z];
  __bf16* __restrict__ Wt = p.d[blockIdx.z];
  const float sc = p.sc[blockIdx.z];
  __shared__ float tile[32][33];
  const int tx = threadIdx.x & 31, ty = threadIdx.x >> 5;
  const int n0 = blockIdx.x * 32, k0 = blockIdx.y * 32;
#pragma unroll
  for (int j = 0; j < 4; ++j)
    tile[ty + j * 8][tx] = W[(size_t)(k0 + ty + j * 8) * 2048 + n0 + tx];
  __syncthreads();
#pragma unroll
  for (int j = 0; j < 4; ++j)
    Wt[(size_t)(n0 + ty + j * 8) * 2048 + k0 + tx] = (__bf16)(tile[tx][ty + j * 8] * sc);
}

// ---------- RMSNorm: f32 in -> bf16 out, D=2048, one block per row ----------
__global__ __launch_bounds__(256) void rmsnorm_k(
    const float* __restrict__ x, const float* __restrict__ scale,
    __bf16* __restrict__ out) {
  const int row = blockIdx.x, t = threadIdx.x;
  const float4* xr = (const float4*)(x + (size_t)row * 2048);
  float4 a = xr[t], b2 = xr[t + 256];
  float ss = a.x * a.x + a.y * a.y + a.z * a.z + a.w * a.w +
             b2.x * b2.x + b2.y * b2.y + b2.z * b2.z + b2.w * b2.w;
#pragma unroll
  for (int ofs = 32; ofs; ofs >>= 1) ss += __shfl_xor(ss, ofs, 64);
  __shared__ float red[4];
  if ((t & 63) == 0) red[t >> 6] = ss;
  __syncthreads();
  ss = red[0] + red[1] + red[2] + red[3];
  const float rs = rsqrtf(ss * (1.f / 2048.f) + 1e-5f);
  const float4* sr = (const float4*)scale;
  float4 s1 = sr[t], s2 = sr[t + 256];
  __bf16* orow = out + (size_t)row * 2048;
  orow[t * 4 + 0] = (__bf16)(a.x * rs * s1.x);
  orow[t * 4 + 1] = (__bf16)(a.y * rs * s1.y);
  orow[t * 4 + 2] = (__bf16)(a.z * rs * s1.z);
  orow[t * 4 + 3] = (__bf16)(a.w * rs * s1.w);
  orow[(t + 256) * 4 + 0] = (__bf16)(b2.x * rs * s2.x);
  orow[(t + 256) * 4 + 1] = (__bf16)(b2.y * rs * s2.y);
  orow[(t + 256) * 4 + 2] = (__bf16)(b2.z * rs * s2.z);
  orow[(t + 256) * 4 + 3] = (__bf16)(b2.w * rs * s2.w);
}

// ---------- GEMM v2: 256(M)x128(N) tile, BK=64, 8 waves, 8-phase counted-vmcnt
// Grid 16x16 = 256 blocks = ONE perfect dispatch round at 1 block/CU.
// LDS slots per dbuf: 0=B (128x64), 1=A rows 0..127, 2=A rows 128..255; 96KB.
// Stage map: ph0 -> slot2(t+1, buf^1); ph1 -> slot0(t+2); ph2 -> slot1(t+2).
// 6 loads/tile; prologue 10 outstanding -> vmcnt(4); steady ph3 queue=10,
// vmcnt(4) drains oldest 6 = tile t+1 complete. All 16 ds_reads in ph0,
// drained by ph0 lgkmcnt(0) before any same-buffer re-stage (ph1/ph2).
// Per wave (wr=w>>1 M, wc=w&1 N): 64x64 output, acc[4][4] = 64 VGPR.
template <bool OUTF32, bool HASBIAS, bool HASRES, bool SILU, bool VTRANS>
__global__ __launch_bounds__(512, 2) void gemm_bt2(
    const __bf16* __restrict__ A, const __bf16* __restrict__ Bt,
    const float* __restrict__ bias, const float* __restrict__ res,
    const __bf16* __restrict__ ew, void* __restrict__ Cout,
    int M, int N, int Kd) {
  __shared__ __attribute__((aligned(16))) char lds[2][3][16384];

  const int tid = threadIdx.x;
  const int w = tid >> 6, l = tid & 63;
  const int wr = w >> 1, wc = w & 1;
  const int lm = l & 15, lq = l >> 4;

  // XCD-bijective chunked swizzle (256 blocks): each XCD gets 2 N-panels
  // (2x128 cols x 2048 K x 2B = 1MB B-data, L2-resident) x 16 M-tiles.
  const int flat = blockIdx.y * 16 + blockIdx.x;
  const int swz = (flat & 7) * 32 + (flat >> 3);
  const int bx = swz >> 4, by = swz & 15;
  const int N0 = bx * 128, M0 = by * 256;

  const int srow = w * 8 + (l >> 3);             // 0..63 (load0); +64 (load1)
  const int scol = ((l & 7) ^ (l >> 3)) * 8;     // pre-swizzled col
  const __bf16* aS = A + (size_t)(M0 + srow) * Kd + scol;
  const __bf16* bS = Bt + (size_t)(N0 + srow) * Kd + scol;

  auto stageHT = [&](int t, int s, int db) {
    char* dst = lds[db][s] + w * 1024;
    const __bf16* src = (s == 0) ? (bS + t * 64)
                                 : (aS + (size_t)(s - 1) * 128 * Kd + t * 64);
    __builtin_amdgcn_global_load_lds(GLB_AS(src), LDS_AS(dst), 16, 0, 0);
    __builtin_amdgcn_global_load_lds(GLB_AS(src + (size_t)64 * Kd), LDS_AS(dst + 8192), 16, 0, 0);
  };

  f32x4 acc[4][4];
#pragma unroll
  for (int m = 0; m < 4; ++m)
#pragma unroll
    for (int n = 0; n < 4; ++n)
#pragma unroll
      for (int e = 0; e < 4; ++e) acc[m][n][e] = 0.f;

  const int swzr = (lm & 7) << 4;
  const int c0 = (lq * 16) ^ swzr;
  const int c1 = ((64 + lq * 16)) ^ swzr;
  const int arow = (wr & 1) * 8192 + lm * 128;   // A slot = 1 + (wr>>1)
  const int brow = wc * 8192 + lm * 128;

  stageHT(0, 0, 0); stageHT(0, 1, 0); stageHT(0, 2, 0);
  stageHT(1, 0, 1); stageHT(1, 1, 1);
  asm volatile("s_waitcnt vmcnt(4)" ::: "memory");
  __builtin_amdgcn_s_barrier();

  const int NT = Kd >> 6;
  bf16x8 af[4][2], bfr[4][2];

#define BAR()                                            \
  do {                                                   \
    asm volatile("" ::: "memory");                       \
    __builtin_amdgcn_s_barrier();                        \
    asm volatile("" ::: "memory");                       \
  } while (0)

#define MFMA_QUAD(MB, NB)                                                          \
  do {                                                                             \
    _Pragma("unroll") for (int m = 0; m < 2; ++m)                                  \
      _Pragma("unroll") for (int n = 0; n < 2; ++n) {                              \
        acc[(MB) + m][(NB) + n] = __builtin_amdgcn_mfma_f32_16x16x32_bf16(         \
            af[(MB) + m][0], bfr[(NB) + n][0], acc[(MB) + m][(NB) + n], 0, 0, 0);  \
        acc[(MB) + m][(NB) + n] = __builtin_amdgcn_mfma_f32_16x16x32_bf16(         \
            af[(MB) + m][1], bfr[(NB) + n][1], acc[(MB) + m][(NB) + n], 0, 0, 0);  \
      }                                                                            \
  } while (0)

#define TILE_BODY(T, BUF)                                                       \
  do {                                                                          \
    const char* Ab = lds[BUF][1 + (wr >> 1)];                                   \
    const char* Bb = lds[BUF][0];                                               \
    /* ph0: read all A(8) + all B(8); stage slot2(T+1)->buf^1; MFMA(0,0) */     \
    _Pragma("unroll") for (int m = 0; m < 4; ++m) {                             \
      af[m][0] = *(const bf16x8*)(Ab + arow + m * 2048 + c0);                   \
      af[m][1] = *(const bf16x8*)(Ab + arow + m * 2048 + c1);                   \
    }                                                                           \
    _Pragma("unroll") for (int n = 0; n < 4; ++n) {                             \
      bfr[n][0] = *(const bf16x8*)(Bb + brow + n * 2048 + c0);                  \
      bfr[n][1] = *(const bf16x8*)(Bb + brow + n * 2048 + c1);                  \
    }                                                                           \
    if ((T) + 1 < NT) stageHT((T) + 1, 2, (BUF) ^ 1);                           \
    BAR();                                                                      \
    __builtin_amdgcn_s_setprio(1);                                              \
    MFMA_QUAD(0, 0);                                                            \
    __builtin_amdgcn_s_setprio(0);                                              \
    asm volatile("s_waitcnt lgkmcnt(0)" ::: "memory");                          \
    BAR();                                                                      \
    /* ph1: stage slot0(T+2); MFMA(0,2) */                                      \
    if ((T) + 2 < NT) stageHT((T) + 2, 0, BUF);                                 \
    BAR();                                                                      \
    __builtin_amdgcn_s_setprio(1);                                              \
    MFMA_QUAD(0, 2);                                                            \
    __builtin_amdgcn_s_setprio(0);                                              \
    BAR();                                                                      \
    /* ph2: stage slot1(T+2); MFMA(2,0) */                                      \
    if ((T) + 2 < NT) stageHT((T) + 2, 1, BUF);                                 \
    BAR();                                                                      \
    __builtin_amdgcn_s_setprio(1);                                              \
    MFMA_QUAD(2, 0);                                                            \
    __builtin_amdgcn_s_setprio(0);                                              \
    BAR();                                                                      \
    /* ph3: MFMA(2,2); counted vmcnt */                                         \
    __builtin_amdgcn_s_setprio(1);                                              \
    MFMA_QUAD(2, 2);                                                            \
    __builtin_amdgcn_s_setprio(0);                                              \
    if ((T) + 2 < NT) { asm volatile("s_waitcnt vmcnt(4)" ::: "memory"); }      \
    else { asm volatile("s_waitcnt vmcnt(0)" ::: "memory"); }                   \
    BAR();                                                                      \
  } while (0)

  for (int tp = 0; tp < NT; tp += 2) {
    TILE_BODY(tp, 0);
    TILE_BODY(tp + 1, 1);
  }
#undef TILE_BODY
#undef MFMA_QUAD
#undef BAR

  // ---- epilogue: per-wave 64x64 at (M0 + wr*64, N0 + wc*64) ----
#pragma unroll
  for (int mt = 0; mt < 4; ++mt) {
#pragma unroll
    for (int nt = 0; nt < 4; ++nt) {
      const int col = N0 + wc * 64 + nt * 16 + lm;
      float bv = 0.f;
      if (HASBIAS) bv = bias[col];
      if (VTRANS) {
        const int rw0 = M0 + wr * 64 + mt * 16 + lq * 4;
        const int bidx = rw0 >> 11, tok = rw0 & 2047;
        bf16x4v pk;
#pragma unroll
        for (int i = 0; i < 4; ++i) pk[i] = (__bf16)(acc[mt][nt][i] + bv);
        *(bf16x4v*)((__bf16*)Cout + ((size_t)(bidx * 2048 + col)) * 2048 + tok) = pk;
      } else {
#pragma unroll
        for (int i = 0; i < 4; ++i) {
          const int row = M0 + wr * 64 + mt * 16 + lq * 4 + i;
          const size_t off = (size_t)row * N + col;
          float v = acc[mt][nt][i] + bv;
          if (HASRES) v += res[off];
          if (SILU) {
            const float x1v = (float)ew[off];
            v = x1v * (1.f / (1.f + __expf(-x1v))) * v;
          }
          if (OUTF32) ((float*)Cout)[off] = v;
          else ((__bf16*)Cout)[off] = (__bf16)v;
        }
      }
    }
  }
}

// ---------- fused QK GEMM: 256^2 tile, BK=64, 8 waves, 8-phase counted-vmcnt ----
// Covers ONLY Q,K (N 0..4095): grid 16x16 = 256 blocks = one perfect round.
// Wq/bq are pre-scaled by QSCL (attn softmax scale folded into Q).
__global__ __launch_bounds__(512, 2) void gemm_qkv(
    const __bf16* __restrict__ A, const __bf16* __restrict__ Bt,
    const float* __restrict__ bq, const float* __restrict__ bk,
    __bf16* __restrict__ Qout, __bf16* __restrict__ Kout, int Kd) {
  __shared__ __attribute__((aligned(16))) char lds[2][4][16384];

  const int tid = threadIdx.x;
  const int w = tid >> 6, l = tid & 63;
  const int wr = w >> 2, wc = w & 3;
  const int lm = l & 15, lq = l >> 4;

  const int flat = blockIdx.y * 16 + blockIdx.x;
  const int swz = (flat & 7) * 32 + (flat >> 3);
  const int bx = swz >> 4, by = swz & 15;
  const int N0 = bx * 256, M0 = by * 256;

  const int srow = w * 8 + (l >> 3);
  const int scol = ((l & 7) ^ (l >> 3)) * 8;
  const __bf16* aS = A + (size_t)(M0 + srow) * Kd + scol;
  const __bf16* bS = Bt + (size_t)(N0 + srow) * Kd + scol;

  auto stageHT = [&](int t, int s, int db) {
    char* dst = lds[db][s] + w * 1024;
    const __bf16* src = (s >= 2) ? (aS + (size_t)(s - 2) * 128 * Kd + t * 64)
                                 : (bS + (size_t)s * 128 * Kd + t * 64);
    __builtin_amdgcn_global_load_lds(GLB_AS(src), LDS_AS(dst), 16, 0, 0);
    __builtin_amdgcn_global_load_lds(GLB_AS(src + (size_t)64 * Kd), LDS_AS(dst + 8192), 16, 0, 0);
  };

  f32x4 acc[8][4];
#pragma unroll
  for (int m = 0; m < 8; ++m)
#pragma unroll
    for (int n = 0; n < 4; ++n)
#pragma unroll
      for (int e = 0; e < 4; ++e) acc[m][n][e] = 0.f;

  const int swzr = (lm & 7) << 4;
  const int c0 = (lq * 16) ^ swzr;
  const int c1 = ((64 + lq * 16)) ^ swzr;
  const int arow = lm * 128;
  const int brow = ((wc & 1) * 64 + lm) * 128;

  stageHT(0, 0, 0); stageHT(0, 1, 0); stageHT(0, 2, 0); stageHT(0, 3, 0);
  stageHT(1, 0, 1); stageHT(1, 1, 1); stageHT(1, 2, 1);
  asm volatile("s_waitcnt vmcnt(6)" ::: "memory");
  __builtin_amdgcn_s_barrier();

  const int NT = Kd >> 6;
  bf16x8 af[4][2], bfr[4][2];

#define BAR()                                            \
  do {                                                   \
    asm volatile("" ::: "memory");                       \
    __builtin_amdgcn_s_barrier();                        \
    asm volatile("" ::: "memory");                       \
  } while (0)

#define MFMA_QUAD(MB, NB)                                                          \
  do {                                                                             \
    _Pragma("unroll") for (int m = 0; m < 4; ++m)                                  \
      _Pragma("unroll") for (int n = 0; n < 2; ++n) {                              \
        acc[(MB) + m][(NB) + n] = __builtin_amdgcn_mfma_f32_16x16x32_bf16(         \
            af[m][0], bfr[(NB) + n][0], acc[(MB) + m][(NB) + n], 0, 0, 0);         \
        acc[(MB) + m][(NB) + n] = __builtin_amdgcn_mfma_f32_16x16x32_bf16(         \
            af[m][1], bfr[(NB) + n][1], acc[(MB) + m][(NB) + n], 0, 0, 0);         \
      }                                                                            \
  } while (0)

#define TILE_BODY(T, BUF)                                                       \
  do {                                                                          \
    const char* Ab = lds[BUF][2 + wr];                                          \
    const char* Bb = lds[BUF][wc >> 1];                                         \
    _Pragma("unroll") for (int m = 0; m < 4; ++m) {                             \
      af[m][0] = *(const bf16x8*)(Ab + arow + m * 2048 + c0);                   \
      af[m][1] = *(const bf16x8*)(Ab + arow + m * 2048 + c1);                   \
    }                                                                           \
    _Pragma("unroll") for (int n = 0; n < 4; ++n) {                             \
      bfr[n][0] = *(const bf16x8*)(Bb + brow + n * 2048 + c0);                  \
      bfr[n][1] = *(const bf16x8*)(Bb + brow + n * 2048 + c1);                  \
    }                                                                           \
    if ((T) + 1 < NT) stageHT((T) + 1, 3, (BUF) ^ 1);                           \
    BAR();                                                                      \
    __builtin_amdgcn_s_setprio(1);                                              \
    MFMA_QUAD(0, 0);                                                            \
    __builtin_amdgcn_s_setprio(0);                                              \
    asm volatile("s_waitcnt lgkmcnt(0)" ::: "memory");                          \
    BAR();                                                                      \
    if ((T) + 2 < NT) stageHT((T) + 2, 0, BUF);                                 \
    BAR();                                                                      \
    __builtin_amdgcn_s_setprio(1);                                              \
    MFMA_QUAD(0, 2);                                                            \
    __builtin_amdgcn_s_setprio(0);                                              \
    BAR();                                                                      \
    _Pragma("unroll") for (int m = 0; m < 4; ++m) {                             \
      af[m][0] = *(const bf16x8*)(Ab + arow + (m + 4) * 2048 + c0);             \
      af[m][1] = *(const bf16x8*)(Ab + arow + (m + 4) * 2048 + c1);             \
    }                                                                           \
    if ((T) + 2 < NT) stageHT((T) + 2, 1, BUF);                                 \
    BAR();                                                                      \
    __builtin_amdgcn_s_setprio(1);                                              \
    MFMA_QUAD(4, 0);                                                            \
    __builtin_amdgcn_s_setprio(0);                                              \
    asm volatile("s_waitcnt lgkmcnt(0)" ::: "memory");                          \
    BAR();                                                                      \
    if ((T) + 2 < NT) stageHT((T) + 2, 2, BUF);                                 \
    BAR();                                                                      \
    __builtin_amdgcn_s_setprio(1);                                              \
    MFMA_QUAD(4, 2);                                                            \
    __builtin_amdgcn_s_setprio(0);                                              \
    if ((T) + 2 < NT) { asm volatile("s_waitcnt vmcnt(6)" ::: "memory"); }      \
    else { asm volatile("s_waitcnt vmcnt(0)" ::: "memory"); }                   \
    BAR();                                                                      \
  } while (0)

  for (int tp = 0; tp < NT; tp += 2) {
    TILE_BODY(tp, 0);
    TILE_BODY(tp + 1, 1);
  }
#undef TILE_BODY
#undef MFMA_QUAD
#undef BAR

  const int seg = N0 >> 11;               // 0:Q 1:K
  const int nbase = N0 & 2047;
  const float* bb = (seg == 0) ? bq : bk;
  const float bsc = (seg == 0) ? QSCL : 1.f;   // bq pre-scaled like Wq
  __bf16* dst = (seg == 0) ? Qout : Kout;
#pragma unroll
  for (int m = 0; m < 8; ++m) {
#pragma unroll
    for (int n = 0; n < 4; ++n) {
      const int col = nbase + wc * 64 + n * 16 + lm;
      const float bvv = bb[col] * bsc;
#pragma unroll
      for (int i = 0; i < 4; ++i) {
        const int row = M0 + wr * 128 + m * 16 + lq * 4 + i;
        dst[(size_t)row * 2048 + col] = (__bf16)(acc[m][n][i] + bvv);
      }
    }
  }
}

// ---------- MFMA flash attention v8: ones-MFMA rowsum + pre-scaled Q ---------
__global__ __launch_bounds__(256, 2) void attn_mfma(
    const __bf16* __restrict__ Q, const __bf16* __restrict__ K,
    const __bf16* __restrict__ Vt, __bf16* __restrict__ O) {
  __shared__ __attribute__((aligned(16))) char KsL[2][16 * 1024];
  __shared__ __attribute__((aligned(16))) char VsL[2][16 * 1024];

  const int t = threadIdx.x;
  const int w = t >> 6, l = t & 63;
  const int lm = l & 15, quad = l >> 4;
  const int flat = (blockIdx.z * gridDim.y + blockIdx.y) * gridDim.x + blockIdx.x;
  const int swz = (flat & 7) * 64 + (flat >> 3);
  const int b = swz >> 8;
  const int h = (swz >> 4) & 15;
  const int q0 = (swz & 15) * 128;
  const size_t Ds = 2048;
  const size_t hoff = (size_t)h * 128;
  const size_t bbase = (size_t)b * 2048;
  const int slq = (lm << 2) | quad;
  const int sl16 = (slq ^ ((slq >> 3) & 7)) * 16;   // swizzled read offset

  const int slog = l ^ ((l >> 3) & 7);
  const int krow = slog >> 2, kcol = (slog & 3) * 8;
  const int vth = l & 3, vd = l >> 2;

  bf16x8 onesv;
#pragma unroll
  for (int i = 0; i < 8; ++i) onesv[i] = (__bf16)1.0f;

  bf16x8 qf[2][4];
#pragma unroll
  for (int ntq = 0; ntq < 2; ++ntq)
#pragma unroll
    for (int ks = 0; ks < 4; ++ks)
      qf[ntq][ks] = *(const bf16x8*)(Q + (bbase + q0 + w * 32 + ntq * 16 + lm) * Ds + hoff + ks * 32 + quad * 8);

  f32x4 oacc[2][8];
#pragma unroll
  for (int ntq = 0; ntq < 2; ++ntq)
#pragma unroll
    for (int nv = 0; nv < 8; ++nv)
#pragma unroll
      for (int e = 0; e < 4; ++e) oacc[ntq][nv][e] = 0.f;
  f32x4 lacc[2];
#pragma unroll
  for (int ntq = 0; ntq < 2; ++ntq)
#pragma unroll
    for (int e = 0; e < 4; ++e) lacc[ntq][e] = 0.f;

  bf16x8 vreg[4];

  auto loadV = [&](int kt) {
#pragma unroll
    for (int i = 0; i < 4; ++i) {
      const int chunk = w * 4 + i;
      const int nv = chunk >> 1, c = chunk & 1;
      vreg[i] = *(const bf16x8*)(Vt + (bbase + hoff + nv * 16 + vd) * Ds + kt + c * 32 + vth * 8);
    }
  };
  auto stageK = [&](int kt, char* Kb) {
#pragma unroll
    for (int i = 0; i < 4; ++i) {
      const __bf16* src = K + (bbase + kt + i * 16 + krow) * Ds + hoff + w * 32 + kcol;
      __builtin_amdgcn_global_load_lds(GLB_AS(src), LDS_AS(Kb + (i * 4 + w) * 1024), 16, 0, 0);
    }
  };
  auto writeV = [&](char* Vb) {
    const int slot_a = (vd << 2) | ((vth & 1) << 1);
    const int o_a = (slot_a ^ ((vd >> 1) & 7)) * 16 + (vth >> 1) * 8;
#pragma unroll
    for (int i = 0; i < 4; ++i) {
      char* base = Vb + (w * 4 + i) * 1024;
      uint4 u = *(const uint4*)&vreg[i];
      *(uint2*)(base + o_a) = make_uint2(u.x, u.y);
      *(uint2*)(base + (o_a ^ 16)) = make_uint2(u.z, u.w);
    }
  };

  loadV(0);
  stageK(0, KsL[0]);
  writeV(VsL[0]);

  for (int it = 0; it < 32; ++it) {
    __syncthreads();
    const int cur = it & 1;
    const bool more = (it + 1) < 32;
    if (more) { loadV((it + 1) * 64); stageK((it + 1) * 64, KsL[(it + 1) & 1]); }

    const char* Kb = KsL[cur];
    const char* Vb = VsL[cur];

    f32x4 st[4][2];
#pragma unroll
    for (int mtk = 0; mtk < 4; ++mtk)
#pragma unroll
      for (int ntq = 0; ntq < 2; ++ntq)
#pragma unroll
        for (int e = 0; e < 4; ++e) st[mtk][ntq][e] = 0.f;
    __builtin_amdgcn_s_setprio(1);
#pragma unroll
    for (int ks = 0; ks < 4; ++ks) {
#pragma unroll
      for (int mtk = 0; mtk < 4; ++mtk) {
        bf16x8 kf = *(const bf16x8*)(Kb + (mtk * 4 + ks) * 1024 + sl16);
        st[mtk][0] = __builtin_amdgcn_mfma_f32_16x16x32_bf16(kf, qf[0][ks], st[mtk][0], 0, 0, 0);
        st[mtk][1] = __builtin_amdgcn_mfma_f32_16x16x32_bf16(kf, qf[1][ks], st[mtk][1], 0, 0, 0);
      }
    }
    __builtin_amdgcn_s_setprio(0);

#pragma unroll
    for (int c = 0; c < 2; ++c) {
      bf16x8 pf[2];
#pragma unroll
      for (int ntq = 0; ntq < 2; ++ntq) {
#pragma unroll
        for (int half = 0; half < 2; ++half) {
          const f32x4 sv = st[c * 2 + half][ntq];
#pragma unroll
          for (int r = 0; r < 4; ++r)
            pf[ntq][half * 4 + r] = (__bf16)exp2f(sv[r]);
        }
      }
      __builtin_amdgcn_s_setprio(1);
      lacc[0] = __builtin_amdgcn_mfma_f32_16x16x32_bf16(pf[0], onesv, lacc[0], 0, 0, 0);
      lacc[1] = __builtin_amdgcn_mfma_f32_16x16x32_bf16(pf[1], onesv, lacc[1], 0, 0, 0);
#pragma unroll
      for (int nv = 0; nv < 8; ++nv) {
        bf16x8 vf = *(const bf16x8*)(Vb + (nv * 2 + c) * 1024 + sl16);
        oacc[0][nv] = __builtin_amdgcn_mfma_f32_16x16x32_bf16(pf[0], vf, oacc[0][nv], 0, 0, 0);
        oacc[1][nv] = __builtin_amdgcn_mfma_f32_16x16x32_bf16(pf[1], vf, oacc[1][nv], 0, 0, 0);
      }
      __builtin_amdgcn_s_setprio(0);
    }

    if (more) writeV(VsL[(it + 1) & 1]);
  }

  float oinv[2][4];
#pragma unroll
  for (int ntq = 0; ntq < 2; ++ntq)
#pragma unroll
    for (int r = 0; r < 4; ++r)
      oinv[ntq][r] = 1.f / lacc[ntq][r];

#pragma unroll
  for (int ntq = 0; ntq < 2; ++ntq)
#pragma unroll
    for (int nv = 0; nv < 8; ++nv)
#pragma unroll
      for (int r = 0; r < 4; ++r) {
        const int qrow = q0 + w * 32 + ntq * 16 + quad * 4 + r;
        O[(bbase + qrow) * Ds + hoff + nv * 16 + lm] = (__bf16)(oacc[ntq][nv][r] * oinv[ntq][r]);
      }
}

// ---------- launch ----------
extern "C" void kernel_launch(void* const* d_in, const int* in_sizes, int n_in,
                              void* d_out, int out_size, void* d_ws, size_t ws_size,
                              hipStream_t stream) {
  const float* x      = (const float*)d_in[0];
  const float* Wq     = (const float*)d_in[1];
  const float* bq     = (const float*)d_in[2];
  const float* Wk     = (const float*)d_in[3];
  const float* bk     = (const float*)d_in[4];
  const float* Wv     = (const float*)d_in[5];
  const float* bv     = (const float*)d_in[6];
  const float* Wo     = (const float*)d_in[7];
  const float* bo     = (const float*)d_in[8];
  const float* scale1 = (const float*)d_in[9];
  const float* scale2 = (const float*)d_in[10];
  const float* W1     = (const float*)d_in[11];
  const float* W2     = (const float*)d_in[12];
  const float* W3     = (const float*)d_in[13];

  const int M = 4096, N = 2048, Kd = 2048;
  char* ws = (char*)d_ws;
  const size_t WT_B = (size_t)2048 * 2048 * 2;   // 8 MB
  const size_t ACT_B = (size_t)4096 * 2048 * 2;  // 16 MB
  __bf16* wt[7];
  size_t off = 0;
  for (int i = 0; i < 7; ++i) { wt[i] = (__bf16*)(ws + off); off += WT_B; }
  __bf16* hn1  = (__bf16*)(ws + off); off += ACT_B;
  __bf16* Qb   = (__bf16*)(ws + off); off += ACT_B;
  __bf16* Kb   = (__bf16*)(ws + off); off += ACT_B;
  __bf16* VtG  = (__bf16*)(ws + off); off += ACT_B;
  __bf16* attn = (__bf16*)(ws + off); off += ACT_B;
  __bf16* hn2  = (__bf16*)(ws + off); off += ACT_B;
  __bf16* x1b  = (__bf16*)(ws + off); off += ACT_B;
  __bf16* fmb  = (__bf16*)(ws + off); off += ACT_B;

  dim3 tb(256);
  {
    TP p;
    p.s[0] = Wq; p.s[1] = Wk; p.s[2] = Wv; p.s[3] = Wo; p.s[4] = W1; p.s[5] = W2; p.s[6] = W3;
    for (int i = 0; i < 7; ++i) { p.d[i] = wt[i]; p.sc[i] = 1.f; }
    p.sc[0] = QSCL;                       // fold softmax scale into Wq
    transpose_convert_all<<<dim3(64, 64, 7), tb, 0, stream>>>(p);
  }

  rmsnorm_k<<<4096, tb, 0, stream>>>(x, scale1, hn1);

  // QK GEMM: 256^2 8-phase over N 0..4095, 256 blocks = 1 perfect round
  gemm_qkv<<<dim3(16, 16), dim3(512), 0, stream>>>(hn1, wt[0], bq, bk, Qb, Kb, Kd);
  // V GEMM: 256x128 8-phase, transposed epilogue, 256 blocks = 1 perfect round
  gemm_bt2<false, true, false, false, true><<<dim3(16, 16), dim3(512), 0, stream>>>(
      hn1, wt[2], bv, nullptr, nullptr, VtG, M, 2048, Kd);

  dim3 ag(2048 / 128, 16, 2);
  attn_mfma<<<ag, tb, 0, stream>>>(Qb, Kb, VtG, attn);

  dim3 gg2(16, 16);
  // h2 = x + attn@Wo + bo  -> d_out (f32 scratch)
  gemm_bt2<true, true, true, false, false><<<gg2, dim3(512), 0, stream>>>(
      attn, wt[3], bo, x, nullptr, d_out, M, N, Kd);

  rmsnorm_k<<<4096, tb, 0, stream>>>((const float*)d_out, scale2, hn2);

  gemm_bt2<false, false, false, false, false><<<gg2, dim3(512), 0, stream>>>(
      hn2, wt[4], nullptr, nullptr, nullptr, x1b, M, N, Kd);
  gemm_bt2<false, false, false, true, false><<<gg2, dim3(512), 0, stream>>>(
      x1b, wt[5], nullptr, nullptr, x1b, fmb, M, N, Kd);
  gemm_bt2<true, false, true, false, false><<<gg2, dim3(512), 0, stream>>>(
      fmb, wt[6], nullptr, x, nullptr, d_out, M, N, Kd);
}